// Round 3
// baseline (621.408 us; speedup 1.0000x reference)
//
#include <hip/hip_runtime.h>
#include <math.h>

#define HH 32
#define WW 32
#define HWSZ 1024      // H*W
#define CC 384
#define NHEAD 12
#define NGROUP 6
#define HC 32
#define GC 64
#define NS 1024        // n_sample
#define ATTN_SCALE 0.17677669529663687f  // 32^-0.5

// ---------------------------------------------------------------------------
// 1x1-conv GEMM: Y[b,o,n] = sum_c W[o,c] * X[b,c,n] + bias[o]
// M=K=384, N=1024. 64x64 tile, BK=32, 4x4 microtile.
// dual=1: blockIdx.z = batch*2 + which, which selects (W1,b1,Y1).
// ---------------------------------------------------------------------------
template<int DUAL>
__global__ __launch_bounds__(256) void gemm_bias_kernel(
    const float* __restrict__ W0, const float* __restrict__ bias0,
    const float* __restrict__ W1, const float* __restrict__ bias1,
    const float* __restrict__ X, float* __restrict__ Y0, float* __restrict__ Y1)
{
    int bz, which;
    if (DUAL) { bz = blockIdx.z >> 1; which = blockIdx.z & 1; }
    else      { bz = blockIdx.z;      which = 0; }
    const float* W    = which ? W1 : W0;
    const float* bias = which ? bias1 : bias0;
    float* Y          = which ? Y1 : Y0;

    const float* Xb = X + (size_t)bz * CC * 1024;
    float* Yb = Y + (size_t)bz * CC * 1024;
    const int tm = blockIdx.y * 64;
    const int tn = blockIdx.x * 64;
    const int tid = threadIdx.x;
    const int tx = tid & 15, ty = tid >> 4;

    __shared__ float sW[32][68];   // [k][m]
    __shared__ float sX[32][68];   // [k][n]

    float acc[4][4] = {};

    for (int k0 = 0; k0 < CC; k0 += 32) {
        {   // W tile: 64 m x 32 k, thread loads 8 consecutive k (2 float4)
            int idx = tid * 8;
            int m = idx >> 5;
            int kk = idx & 31;
            float4 wa = *(const float4*)&W[(size_t)(tm + m) * CC + k0 + kk];
            float4 wb = *(const float4*)&W[(size_t)(tm + m) * CC + k0 + kk + 4];
            sW[kk + 0][m] = wa.x; sW[kk + 1][m] = wa.y;
            sW[kk + 2][m] = wa.z; sW[kk + 3][m] = wa.w;
            sW[kk + 4][m] = wb.x; sW[kk + 5][m] = wb.y;
            sW[kk + 6][m] = wb.z; sW[kk + 7][m] = wb.w;
        }
        {   // X tile: 32 k x 64 n, thread loads 8 consecutive n (2 float4)
            int idx = tid * 8;
            int kk = idx >> 6;
            int n = idx & 63;
            *(float4*)&sX[kk][n]     = *(const float4*)&Xb[(size_t)(k0 + kk) * 1024 + tn + n];
            *(float4*)&sX[kk][n + 4] = *(const float4*)&Xb[(size_t)(k0 + kk) * 1024 + tn + n + 4];
        }
        __syncthreads();
#pragma unroll
        for (int kk = 0; kk < 32; ++kk) {
            float a[4], bb[4];
            *(float4*)a  = *(const float4*)&sW[kk][ty * 4];
            *(float4*)bb = *(const float4*)&sX[kk][tx * 4];
#pragma unroll
            for (int i = 0; i < 4; ++i)
#pragma unroll
                for (int j = 0; j < 4; ++j)
                    acc[i][j] += a[i] * bb[j];
        }
        __syncthreads();
    }

#pragma unroll
    for (int i = 0; i < 4; ++i) {
        int m = tm + ty * 4 + i;
        float bv = bias[m];
        float4 r;
        r.x = acc[i][0] + bv; r.y = acc[i][1] + bv;
        r.z = acc[i][2] + bv; r.w = acc[i][3] + bv;
        *(float4*)&Yb[(size_t)m * 1024 + tn + tx * 4] = r;
    }
}

// ---------------------------------------------------------------------------
// Depthwise 7x7 conv on q viewed as [12, 64, 32, 32]; zero pad 3.
// ---------------------------------------------------------------------------
__global__ __launch_bounds__(256) void dwconv_kernel(
    const float* __restrict__ q, const float* __restrict__ dww,
    const float* __restrict__ dwb, float* __restrict__ oconv)
{
    const int bc = blockIdx.x;           // 0..767
    const int bg = bc >> 6, c = bc & 63;
    const int b = bg / 6, g = bg % 6;
    const float* plane = q + ((size_t)b * CC + g * 64 + c) * 1024;

    __shared__ float sp[1024];
    __shared__ float sw[49];
    const int tid = threadIdx.x;
    for (int i = tid; i < 1024; i += 256) sp[i] = plane[i];
    if (tid < 49) sw[tid] = dww[c * 49 + tid];
    __syncthreads();

    const float bias = dwb[c];
    for (int i = tid; i < 1024; i += 256) {
        int y = i >> 5, x = i & 31;
        float s = 0.f;
#pragma unroll
        for (int ky = 0; ky < 7; ++ky) {
            int yy = y + ky - 3;
            if (yy < 0 || yy > 31) continue;
#pragma unroll
            for (int kx = 0; kx < 7; ++kx) {
                int xx = x + kx - 3;
                if (xx < 0 || xx > 31) continue;
                s += sp[yy * 32 + xx] * sw[ky * 7 + kx];
            }
        }
        oconv[(size_t)bc * 1024 + i] = s + bias;
    }
}

// ---------------------------------------------------------------------------
// LayerNorm(64 ch) + exact GELU + 1x1->2ch + tanh*2/32 + ref points.
// grid (12, 4); one thread per pixel, channel column held in registers.
// ---------------------------------------------------------------------------
__global__ __launch_bounds__(256) void offset_kernel(
    const float* __restrict__ oconv, const float* __restrict__ lng,
    const float* __restrict__ lnb, const float* __restrict__ pw,
    float* __restrict__ pos)
{
    const int bg = blockIdx.x;
    const int px = blockIdx.y * 256 + threadIdx.x;
    const float* base = oconv + (size_t)bg * 64 * 1024 + px;

    float col[64];
    float sum = 0.f;
#pragma unroll
    for (int c = 0; c < 64; ++c) { col[c] = base[(size_t)c * 1024]; sum += col[c]; }
    float mu = sum * (1.f / 64.f);
    float var = 0.f;
#pragma unroll
    for (int c = 0; c < 64; ++c) { float d = col[c] - mu; var += d * d; }
    float inv = rsqrtf(var * (1.f / 64.f) + 1e-5f);
    float offy = 0.f, offx = 0.f;
#pragma unroll
    for (int c = 0; c < 64; ++c) {
        float v = (col[c] - mu) * inv * lng[c] + lnb[c];
        float g = 0.5f * v * (1.f + erff(v * 0.70710678118654752440f));
        offy += g * pw[c];
        offx += g * pw[64 + c];
    }
    offy = tanhf(offy) * (2.0f / 32.0f);
    offx = tanhf(offx) * (2.0f / 32.0f);
    int y = px >> 5, x = px & 31;
    float ry = ((y + 0.5f) / 32.f) * 2.f - 1.f;
    float rx = ((x + 0.5f) / 32.f) * 2.f - 1.f;
    pos[((size_t)bg * 1024 + px) * 2 + 0] = offy + ry;
    pos[((size_t)bg * 1024 + px) * 2 + 1] = offx + rx;
}

// ---------------------------------------------------------------------------
// Bilinear grid-sample of x at pos (align_corners=True, zeros pad).
// ---------------------------------------------------------------------------
__global__ __launch_bounds__(256) void sample_kernel(
    const float* __restrict__ x, const float* __restrict__ pos,
    float* __restrict__ xs)
{
    const int idx = blockIdx.x * 256 + threadIdx.x;   // 786432 total
    const int s = idx & 1023;
    const int bc = idx >> 10;
    const int c = bc % CC;
    const int b = bc / CC;
    const int bg = b * 6 + (c >> 6);

    float py = pos[((size_t)bg * 1024 + s) * 2 + 0];
    float px = pos[((size_t)bg * 1024 + s) * 2 + 1];
    float gx = (px + 1.f) * 0.5f * 31.f;
    float gy = (py + 1.f) * 0.5f * 31.f;
    float x0f = floorf(gx), y0f = floorf(gy);
    float wx = gx - x0f, wy = gy - y0f;
    int x0 = (int)x0f, y0 = (int)y0f;

    const float* plane = x + (size_t)bc * 1024;
    float acc = 0.f;
    if ((unsigned)x0       <= 31u && (unsigned)y0       <= 31u) acc += plane[y0 * 32 + x0]           * (1.f - wx) * (1.f - wy);
    if ((unsigned)(x0 + 1) <= 31u && (unsigned)y0       <= 31u) acc += plane[y0 * 32 + x0 + 1]       * wx * (1.f - wy);
    if ((unsigned)x0       <= 31u && (unsigned)(y0 + 1) <= 31u) acc += plane[(y0 + 1) * 32 + x0]     * (1.f - wx) * wy;
    if ((unsigned)(x0 + 1) <= 31u && (unsigned)(y0 + 1) <= 31u) acc += plane[(y0 + 1) * 32 + x0 + 1] * wx * wy;
    xs[idx] = acc;
}

// ---------------------------------------------------------------------------
// Attention: block per (bh, 8-query tile). Keys n0=tid*4 (float4 loads).
// Probs chunked through 8KB LDS; softmax via shfl+LDS reduce.
// ---------------------------------------------------------------------------
__global__ __launch_bounds__(256) void attn_kernel(
    const float* __restrict__ q, const float* __restrict__ k,
    const float* __restrict__ v, const float* __restrict__ pos,
    const float* __restrict__ rpe, float* __restrict__ out)
{
    const int bh = blockIdx.y;           // 0..23
    const int m0 = blockIdx.x * 8;
    const int b = bh / 12, head = bh % 12;
    const int bg = b * 6 + (head >> 1);
    const int tid = threadIdx.x;
    const int lane = tid & 63, wv = tid >> 6;
    const int n0 = tid * 4;

    const float* qb = q + ((size_t)b * CC + head * 32) * 1024;
    const float* kb = k + ((size_t)b * CC + head * 32) * 1024;
    const float* vb = v + ((size_t)b * CC + head * 32) * 1024;
    const float* rp = rpe + (size_t)head * (63 * 63);
    const float* pg = pos + (size_t)bg * 1024 * 2;

    __shared__ float sq[8][40];          // [mq][hc], stride 40 keeps b128 align
    __shared__ float sp[8][260];         // prob chunk (256 keys, padded)
    __shared__ float rmax[4][8], rsum[4][8];

    {
        int hc = tid >> 3, mq = tid & 7;
        sq[mq][hc] = qb[(size_t)hc * 1024 + m0 + mq];
    }
    __syncthreads();

    // ---- scores: QK^T, keys n0..n0+3 ----
    float sc[8][4] = {};
#pragma unroll
    for (int hc = 0; hc < 32; hc += 4) {
        float4 k0 = *(const float4*)&kb[(size_t)(hc + 0) * 1024 + n0];
        float4 k1 = *(const float4*)&kb[(size_t)(hc + 1) * 1024 + n0];
        float4 k2 = *(const float4*)&kb[(size_t)(hc + 2) * 1024 + n0];
        float4 k3 = *(const float4*)&kb[(size_t)(hc + 3) * 1024 + n0];
#pragma unroll
        for (int mq = 0; mq < 8; ++mq) {
            float4 q4 = *(const float4*)&sq[mq][hc];
            sc[mq][0] += q4.x * k0.x + q4.y * k1.x + q4.z * k2.x + q4.w * k3.x;
            sc[mq][1] += q4.x * k0.y + q4.y * k1.y + q4.z * k2.y + q4.w * k3.y;
            sc[mq][2] += q4.x * k0.z + q4.y * k1.z + q4.z * k2.z + q4.w * k3.z;
            sc[mq][3] += q4.x * k0.w + q4.y * k1.w + q4.z * k2.w + q4.w * k3.w;
        }
    }

    // ---- query reference points ----
    float qyv[8], qxv[8];
#pragma unroll
    for (int mq = 0; mq < 8; ++mq) {
        int m = m0 + mq;
        qyv[mq] = (((m >> 5) + 0.5f) / 32.f) * 2.f - 1.f;
        qxv[mq] = (((m & 31) + 0.5f) / 32.f) * 2.f - 1.f;
    }

    // ---- scale + RPE bias (pos loaded as 2x float4) ----
    float4 p01 = *(const float4*)&pg[n0 * 2];
    float4 p23 = *(const float4*)&pg[n0 * 2 + 4];
    float pyv[4] = {p01.x, p01.z, p23.x, p23.z};
    float pxv[4] = {p01.y, p01.w, p23.y, p23.w};
#pragma unroll
    for (int j = 0; j < 4; ++j) {
        float py = pyv[j], px = pxv[j];
#pragma unroll
        for (int mq = 0; mq < 8; ++mq) {
            float dy = (qyv[mq] - py) * 0.5f;
            float dx = (qxv[mq] - px) * 0.5f;
            float gx = (dx + 1.f) * 31.f;
            float gy = (dy + 1.f) * 31.f;
            float x0f = floorf(gx), y0f = floorf(gy);
            float wx = gx - x0f, wy = gy - y0f;
            int x0 = (int)x0f, y0 = (int)y0f;
            float bias = 0.f;
            if ((unsigned)x0       <= 62u && (unsigned)y0       <= 62u) bias += rp[y0 * 63 + x0]           * (1.f - wx) * (1.f - wy);
            if ((unsigned)(x0 + 1) <= 62u && (unsigned)y0       <= 62u) bias += rp[y0 * 63 + x0 + 1]       * wx * (1.f - wy);
            if ((unsigned)x0       <= 62u && (unsigned)(y0 + 1) <= 62u) bias += rp[(y0 + 1) * 63 + x0]     * (1.f - wx) * wy;
            if ((unsigned)(x0 + 1) <= 62u && (unsigned)(y0 + 1) <= 62u) bias += rp[(y0 + 1) * 63 + x0 + 1] * wx * wy;
            sc[mq][j] = sc[mq][j] * ATTN_SCALE + bias;
        }
    }

    // ---- softmax max ----
    float Mv[8];
#pragma unroll
    for (int mq = 0; mq < 8; ++mq) {
        float mv = fmaxf(fmaxf(sc[mq][0], sc[mq][1]), fmaxf(sc[mq][2], sc[mq][3]));
#pragma unroll
        for (int off = 32; off; off >>= 1) mv = fmaxf(mv, __shfl_xor(mv, off));
        if (lane == 0) rmax[wv][mq] = mv;
    }
    __syncthreads();
#pragma unroll
    for (int mq = 0; mq < 8; ++mq)
        Mv[mq] = fmaxf(fmaxf(rmax[0][mq], rmax[1][mq]), fmaxf(rmax[2][mq], rmax[3][mq]));

    // ---- exp (in regs) + sum ----
#pragma unroll
    for (int mq = 0; mq < 8; ++mq) {
        float s = 0.f;
#pragma unroll
        for (int j = 0; j < 4; ++j) {
            sc[mq][j] = __expf(sc[mq][j] - Mv[mq]);
            s += sc[mq][j];
        }
#pragma unroll
        for (int off = 32; off; off >>= 1) s += __shfl_xor(s, off);
        if (lane == 0) rsum[wv][mq] = s;
    }
    __syncthreads();

    // ---- PV, chunked 4 x 256 keys through sp ----
    const int hcp = tid >> 3, mqp = tid & 7;
    const float invL = 1.f / (rsum[0][mqp] + rsum[1][mqp] + rsum[2][mqp] + rsum[3][mqp]);
    const float* vrow = vb + (size_t)hcp * 1024;
    float acc0 = 0.f, acc1 = 0.f;
#pragma unroll
    for (int c = 0; c < 4; ++c) {
        if (c) __syncthreads();          // protect sp from previous readers
        if ((tid >> 6) == c) {
            int nn = n0 & 255;
#pragma unroll
            for (int mq = 0; mq < 8; ++mq) {
                float4 t; t.x = sc[mq][0]; t.y = sc[mq][1]; t.z = sc[mq][2]; t.w = sc[mq][3];
                *(float4*)&sp[mq][nn] = t;
            }
        }
        __syncthreads();
        const float* vc = vrow + c * 256;
        const float* pr = sp[mqp];
#pragma unroll 4
        for (int i = 0; i < 256; i += 8) {
            float4 pa = *(const float4*)&pr[i];
            float4 va = *(const float4*)&vc[i];
            float4 pb = *(const float4*)&pr[i + 4];
            float4 vb2 = *(const float4*)&vc[i + 4];
            acc0 += pa.x * va.x + pa.y * va.y + pa.z * va.z + pa.w * va.w;
            acc1 += pb.x * vb2.x + pb.y * vb2.y + pb.z * vb2.z + pb.w * vb2.w;
        }
    }
    out[((size_t)b * CC + head * 32 + hcp) * 1024 + m0 + mqp] = (acc0 + acc1) * invL;
}

// ---------------------------------------------------------------------------
extern "C" void kernel_launch(void* const* d_in, const int* in_sizes, int n_in,
                              void* d_out, int out_size, void* d_ws, size_t ws_size,
                              hipStream_t stream) {
    const float* x   = (const float*)d_in[0];
    const float* Wq  = (const float*)d_in[1];
    const float* bq  = (const float*)d_in[2];
    const float* Wk  = (const float*)d_in[3];
    const float* bk  = (const float*)d_in[4];
    const float* Wv  = (const float*)d_in[5];
    const float* bv  = (const float*)d_in[6];
    const float* Wo  = (const float*)d_in[7];
    const float* bo  = (const float*)d_in[8];
    const float* dww = (const float*)d_in[9];
    const float* dwb = (const float*)d_in[10];
    const float* lng = (const float*)d_in[11];
    const float* lnb = (const float*)d_in[12];
    const float* pw  = (const float*)d_in[13];
    const float* rpe = (const float*)d_in[14];

    float* ws = (float*)d_ws;
    const size_t SZ = 786432;           // 2*384*1024
    float* qbuf  = ws;
    float* xs    = ws + 1 * SZ;
    float* kbuf  = ws + 2 * SZ;
    float* vbuf  = ws + 3 * SZ;
    float* abuf  = ws + 4 * SZ;
    float* oconv = ws + 5 * SZ;         // 12*64*1024
    float* pos   = ws + 6 * SZ;         // 12*1024*2

    dim3 gg(16, 6, 2);
    dim3 gg2(16, 6, 4);
    gemm_bias_kernel<0><<<gg, 256, 0, stream>>>(Wq, bq, nullptr, nullptr, x, qbuf, nullptr);
    dwconv_kernel<<<768, 256, 0, stream>>>(qbuf, dww, dwb, oconv);
    offset_kernel<<<dim3(12, 4), 256, 0, stream>>>(oconv, lng, lnb, pw, pos);
    sample_kernel<<<3072, 256, 0, stream>>>(x, pos, xs);
    gemm_bias_kernel<1><<<gg2, 256, 0, stream>>>(Wk, bk, Wv, bv, xs, kbuf, vbuf);
    attn_kernel<<<dim3(128, 24), 256, 0, stream>>>(qbuf, kbuf, vbuf, pos, rpe, abuf);
    gemm_bias_kernel<0><<<gg, 256, 0, stream>>>(Wo, bo, nullptr, nullptr, abuf, (float*)d_out, nullptr);
}

// Round 4
// 492.565 us; speedup vs baseline: 1.2616x; 1.2616x over previous
//
#include <hip/hip_runtime.h>
#include <hip/hip_fp16.h>
#include <math.h>

#define HH 32
#define WW 32
#define HWSZ 1024      // H*W
#define CC 384
#define NHEAD 12
#define NGROUP 6
#define HC 32
#define GC 64
#define NS 1024        // n_sample
#define ATTN_SCALE 0.17677669529663687f  // 32^-0.5

// ---------------------------------------------------------------------------
// 1x1-conv GEMM: Y[b,o,n] = sum_c W[o,c] * X[b,c,n] + bias[o]
// M=K=384, N=1024. 64m x 32n tile, BK=32, 4x2 microtile.
// DUAL=1: blockIdx.z = batch*2 + which; which selects (W1,b1,Y1).
// ---------------------------------------------------------------------------
template<int DUAL>
__global__ __launch_bounds__(256, 8) void gemm_bias_kernel(
    const float* __restrict__ W0, const float* __restrict__ bias0,
    const float* __restrict__ W1, const float* __restrict__ bias1,
    const float* __restrict__ X, float* __restrict__ Y0, float* __restrict__ Y1)
{
    int bz, which;
    if (DUAL) { bz = blockIdx.z >> 1; which = blockIdx.z & 1; }
    else      { bz = blockIdx.z;      which = 0; }
    const float* W    = which ? W1 : W0;
    const float* bias = which ? bias1 : bias0;
    float* Y          = which ? Y1 : Y0;

    const float* Xb = X + (size_t)bz * CC * 1024;
    float* Yb = Y + (size_t)bz * CC * 1024;
    const int tm = blockIdx.y * 64;
    const int tn = blockIdx.x * 32;
    const int tid = threadIdx.x;
    const int tx = tid & 15, ty = tid >> 4;

    __shared__ float sW[32][68];   // [k][m]
    __shared__ float sX[32][36];   // [k][n]

    float acc[4][2] = {};

    for (int k0 = 0; k0 < CC; k0 += 32) {
        {   // W tile: 64 m x 32 k, thread loads 8 consecutive k (2 float4)
            int idx = tid * 8;
            int m = idx >> 5;
            int kk = idx & 31;
            float4 wa = *(const float4*)&W[(size_t)(tm + m) * CC + k0 + kk];
            float4 wb = *(const float4*)&W[(size_t)(tm + m) * CC + k0 + kk + 4];
            sW[kk + 0][m] = wa.x; sW[kk + 1][m] = wa.y;
            sW[kk + 2][m] = wa.z; sW[kk + 3][m] = wa.w;
            sW[kk + 4][m] = wb.x; sW[kk + 5][m] = wb.y;
            sW[kk + 6][m] = wb.z; sW[kk + 7][m] = wb.w;
        }
        {   // X tile: 32 k x 32 n, thread loads one float4 along n
            int idx = tid * 4;
            int kk = idx >> 5;
            int n = idx & 31;
            *(float4*)&sX[kk][n] = *(const float4*)&Xb[(size_t)(k0 + kk) * 1024 + tn + n];
        }
        __syncthreads();
#pragma unroll
        for (int kk = 0; kk < 32; ++kk) {
            float a[4];
            *(float4*)a = *(const float4*)&sW[kk][ty * 4];
            float b0 = sX[kk][tx * 2], b1 = sX[kk][tx * 2 + 1];
#pragma unroll
            for (int i = 0; i < 4; ++i) {
                acc[i][0] += a[i] * b0;
                acc[i][1] += a[i] * b1;
            }
        }
        __syncthreads();
    }

#pragma unroll
    for (int i = 0; i < 4; ++i) {
        int m = tm + ty * 4 + i;
        float bv = bias[m];
        float2 r; r.x = acc[i][0] + bv; r.y = acc[i][1] + bv;
        *(float2*)&Yb[(size_t)m * 1024 + tn + tx * 2] = r;
    }
}

// ---------------------------------------------------------------------------
// Depthwise 7x7 conv on q viewed as [12, 64, 32, 32]; zero pad 3.
// ---------------------------------------------------------------------------
__global__ __launch_bounds__(256) void dwconv_kernel(
    const float* __restrict__ q, const float* __restrict__ dww,
    const float* __restrict__ dwb, float* __restrict__ oconv)
{
    const int bc = blockIdx.x;           // 0..767
    const int bg = bc >> 6, c = bc & 63;
    const int b = bg / 6, g = bg % 6;
    const float* plane = q + ((size_t)b * CC + g * 64 + c) * 1024;

    __shared__ float sp[1024];
    __shared__ float sw[49];
    const int tid = threadIdx.x;
    for (int i = tid; i < 1024; i += 256) sp[i] = plane[i];
    if (tid < 49) sw[tid] = dww[c * 49 + tid];
    __syncthreads();

    const float bias = dwb[c];
    for (int i = tid; i < 1024; i += 256) {
        int y = i >> 5, x = i & 31;
        float s = 0.f;
#pragma unroll
        for (int ky = 0; ky < 7; ++ky) {
            int yy = y + ky - 3;
            if (yy < 0 || yy > 31) continue;
#pragma unroll
            for (int kx = 0; kx < 7; ++kx) {
                int xx = x + kx - 3;
                if (xx < 0 || xx > 31) continue;
                s += sp[yy * 32 + xx] * sw[ky * 7 + kx];
            }
        }
        oconv[(size_t)bc * 1024 + i] = s + bias;
    }
}

// ---------------------------------------------------------------------------
// LayerNorm(64 ch) + exact GELU + 1x1->2ch + tanh*2/32 + ref points.
// grid (12, 4); one thread per pixel, channel column held in registers.
// ---------------------------------------------------------------------------
__global__ __launch_bounds__(256) void offset_kernel(
    const float* __restrict__ oconv, const float* __restrict__ lng,
    const float* __restrict__ lnb, const float* __restrict__ pw,
    float* __restrict__ pos)
{
    const int bg = blockIdx.x;
    const int px = blockIdx.y * 256 + threadIdx.x;
    const float* base = oconv + (size_t)bg * 64 * 1024 + px;

    float col[64];
    float sum = 0.f;
#pragma unroll
    for (int c = 0; c < 64; ++c) { col[c] = base[(size_t)c * 1024]; sum += col[c]; }
    float mu = sum * (1.f / 64.f);
    float var = 0.f;
#pragma unroll
    for (int c = 0; c < 64; ++c) { float d = col[c] - mu; var += d * d; }
    float inv = rsqrtf(var * (1.f / 64.f) + 1e-5f);
    float offy = 0.f, offx = 0.f;
#pragma unroll
    for (int c = 0; c < 64; ++c) {
        float v = (col[c] - mu) * inv * lng[c] + lnb[c];
        float g = 0.5f * v * (1.f + erff(v * 0.70710678118654752440f));
        offy += g * pw[c];
        offx += g * pw[64 + c];
    }
    offy = tanhf(offy) * (2.0f / 32.0f);
    offx = tanhf(offx) * (2.0f / 32.0f);
    int y = px >> 5, x = px & 31;
    float ry = ((y + 0.5f) / 32.f) * 2.f - 1.f;
    float rx = ((x + 0.5f) / 32.f) * 2.f - 1.f;
    pos[((size_t)bg * 1024 + px) * 2 + 0] = offy + ry;
    pos[((size_t)bg * 1024 + px) * 2 + 1] = offx + rx;
}

// ---------------------------------------------------------------------------
// Bilinear grid-sample of x at pos (align_corners=True, zeros pad).
// ---------------------------------------------------------------------------
__global__ __launch_bounds__(256) void sample_kernel(
    const float* __restrict__ x, const float* __restrict__ pos,
    float* __restrict__ xs)
{
    const int idx = blockIdx.x * 256 + threadIdx.x;   // 786432 total
    const int s = idx & 1023;
    const int bc = idx >> 10;
    const int c = bc % CC;
    const int b = bc / CC;
    const int bg = b * 6 + (c >> 6);

    float py = pos[((size_t)bg * 1024 + s) * 2 + 0];
    float px = pos[((size_t)bg * 1024 + s) * 2 + 1];
    float gx = (px + 1.f) * 0.5f * 31.f;
    float gy = (py + 1.f) * 0.5f * 31.f;
    float x0f = floorf(gx), y0f = floorf(gy);
    float wx = gx - x0f, wy = gy - y0f;
    int x0 = (int)x0f, y0 = (int)y0f;

    const float* plane = x + (size_t)bc * 1024;
    float acc = 0.f;
    if ((unsigned)x0       <= 31u && (unsigned)y0       <= 31u) acc += plane[y0 * 32 + x0]           * (1.f - wx) * (1.f - wy);
    if ((unsigned)(x0 + 1) <= 31u && (unsigned)y0       <= 31u) acc += plane[y0 * 32 + x0 + 1]       * wx * (1.f - wy);
    if ((unsigned)x0       <= 31u && (unsigned)(y0 + 1) <= 31u) acc += plane[(y0 + 1) * 32 + x0]     * (1.f - wx) * wy;
    if ((unsigned)(x0 + 1) <= 31u && (unsigned)(y0 + 1) <= 31u) acc += plane[(y0 + 1) * 32 + x0 + 1] * wx * wy;
    xs[idx] = acc;
}

// ---------------------------------------------------------------------------
// Attention: block per (bh, 8-query tile). R1 structure (scores->exp->bulk
// store->PV) with fp16 prob buffer (LDS ~17.8KB) and branch-free RPE
// (displacements provably land in [0,62) — no bounds checks needed).
// ---------------------------------------------------------------------------
__global__ __launch_bounds__(256, 6) void attn_kernel(
    const float* __restrict__ q, const float* __restrict__ k,
    const float* __restrict__ v, const float* __restrict__ pos,
    const float* __restrict__ rpe, float* __restrict__ out)
{
    const int bh = blockIdx.y;           // 0..23
    const int m0 = blockIdx.x * 8;
    const int b = bh / 12, head = bh % 12;
    const int bg = b * 6 + (head >> 1);
    const int tid = threadIdx.x;
    const int lane = tid & 63, wv = tid >> 6;

    const float* qb = q + ((size_t)b * CC + head * 32) * 1024;
    const float* kb = k + ((size_t)b * CC + head * 32) * 1024;
    const float* vb = v + ((size_t)b * CC + head * 32) * 1024;
    const float* rp = rpe + (size_t)head * (63 * 63);
    const float* pg = pos + (size_t)bg * 1024 * 2;

    __shared__ float sq[32][8];          // [hc][mq]
    __shared__ __half sp[8][1032];       // fp16 unnormalized probs, padded
    __shared__ float rmax[4][8], rsum[4][8];

    {
        int hc = tid >> 3, mq = tid & 7;
        sq[hc][mq] = qb[(size_t)hc * 1024 + m0 + mq];
    }
    __syncthreads();

    // ---- scores: QK^T (keys {tid, tid+256, tid+512, tid+768}) ----
    float sc[8][4];
#pragma unroll
    for (int mq = 0; mq < 8; ++mq)
#pragma unroll
        for (int j = 0; j < 4; ++j) sc[mq][j] = 0.f;

#pragma unroll 4
    for (int hc = 0; hc < 32; ++hc) {
        float qv[8];
#pragma unroll
        for (int mq = 0; mq < 8; ++mq) qv[mq] = sq[hc][mq];
        const float* krow = kb + (size_t)hc * 1024;
#pragma unroll
        for (int j = 0; j < 4; ++j) {
            float kv = krow[tid + j * 256];
#pragma unroll
            for (int mq = 0; mq < 8; ++mq) sc[mq][j] += qv[mq] * kv;
        }
    }

    // ---- query reference points ----
    float qyv[8], qxv[8];
#pragma unroll
    for (int mq = 0; mq < 8; ++mq) {
        int m = m0 + mq;
        qyv[mq] = (((m >> 5) + 0.5f) / 32.f) * 2.f - 1.f;
        qxv[mq] = (((m & 31) + 0.5f) / 32.f) * 2.f - 1.f;
    }

    // ---- scale + RPE bias (branch-free bilinear; gx,gy in (0,62)) ----
#pragma unroll
    for (int j = 0; j < 4; ++j) {
        int n = tid + j * 256;
        float py = pg[n * 2 + 0];
        float px = pg[n * 2 + 1];
#pragma unroll
        for (int mq = 0; mq < 8; ++mq) {
            float gx = (qxv[mq] - px) * 15.5f + 31.f;
            float gy = (qyv[mq] - py) * 15.5f + 31.f;
            float x0f = floorf(gx), y0f = floorf(gy);
            float wx = gx - x0f, wy = gy - y0f;
            int i00 = (int)y0f * 63 + (int)x0f;
            float r00 = rp[i00], r01 = rp[i00 + 1];
            float r10 = rp[i00 + 63], r11 = rp[i00 + 64];
            float top = r00 + (r01 - r00) * wx;
            float bot = r10 + (r11 - r10) * wx;
            sc[mq][j] = sc[mq][j] * ATTN_SCALE + top + (bot - top) * wy;
        }
    }

    // ---- softmax max ----
    float Mv[8];
#pragma unroll
    for (int mq = 0; mq < 8; ++mq) {
        float mv = fmaxf(fmaxf(sc[mq][0], sc[mq][1]), fmaxf(sc[mq][2], sc[mq][3]));
#pragma unroll
        for (int off = 32; off; off >>= 1) mv = fmaxf(mv, __shfl_xor(mv, off));
        if (lane == 0) rmax[wv][mq] = mv;
    }
    __syncthreads();
#pragma unroll
    for (int mq = 0; mq < 8; ++mq)
        Mv[mq] = fmaxf(fmaxf(rmax[0][mq], rmax[1][mq]), fmaxf(rmax[2][mq], rmax[3][mq]));

    // ---- exp, bulk store (fp16), sum ----
#pragma unroll
    for (int mq = 0; mq < 8; ++mq) {
        float s = 0.f;
#pragma unroll
        for (int j = 0; j < 4; ++j) {
            float p = __expf(sc[mq][j] - Mv[mq]);
            sp[mq][tid + j * 256] = __float2half(p);
            s += p;
        }
#pragma unroll
        for (int off = 32; off; off >>= 1) s += __shfl_xor(s, off);
        if (lane == 0) rsum[wv][mq] = s;
    }
    __syncthreads();

    // ---- PV: one (hc, mq) pair per thread, full 1024-key row ----
    {
        const int hcp = tid >> 3, mqp = tid & 7;
        const float invL = 1.f / (rsum[0][mqp] + rsum[1][mqp] + rsum[2][mqp] + rsum[3][mqp]);
        const float* vrow = vb + (size_t)hcp * 1024;
        const __half* prow = sp[mqp];
        float acc0 = 0.f, acc1 = 0.f;
#pragma unroll 4
        for (int i = 0; i < 1024; i += 8) {
            union { uint4 u; __half2 h[4]; } pu;
            pu.u = *(const uint4*)&prow[i];
            float4 va  = *(const float4*)&vrow[i];
            float4 vb2 = *(const float4*)&vrow[i + 4];
            float2 f0 = __half22float2(pu.h[0]);
            float2 f1 = __half22float2(pu.h[1]);
            float2 f2 = __half22float2(pu.h[2]);
            float2 f3 = __half22float2(pu.h[3]);
            acc0 += f0.x * va.x  + f0.y * va.y  + f1.x * va.z  + f1.y * va.w;
            acc1 += f2.x * vb2.x + f2.y * vb2.y + f3.x * vb2.z + f3.y * vb2.w;
        }
        out[((size_t)b * CC + head * 32 + hcp) * 1024 + m0 + mqp] = (acc0 + acc1) * invL;
    }
}

// ---------------------------------------------------------------------------
extern "C" void kernel_launch(void* const* d_in, const int* in_sizes, int n_in,
                              void* d_out, int out_size, void* d_ws, size_t ws_size,
                              hipStream_t stream) {
    const float* x   = (const float*)d_in[0];
    const float* Wq  = (const float*)d_in[1];
    const float* bq  = (const float*)d_in[2];
    const float* Wk  = (const float*)d_in[3];
    const float* bk  = (const float*)d_in[4];
    const float* Wv  = (const float*)d_in[5];
    const float* bv  = (const float*)d_in[6];
    const float* Wo  = (const float*)d_in[7];
    const float* bo  = (const float*)d_in[8];
    const float* dww = (const float*)d_in[9];
    const float* dwb = (const float*)d_in[10];
    const float* lng = (const float*)d_in[11];
    const float* lnb = (const float*)d_in[12];
    const float* pw  = (const float*)d_in[13];
    const float* rpe = (const float*)d_in[14];

    float* ws = (float*)d_ws;
    const size_t SZ = 786432;           // 2*384*1024
    float* qbuf  = ws;
    float* xs    = ws + 1 * SZ;
    float* kbuf  = ws + 2 * SZ;
    float* vbuf  = ws + 3 * SZ;
    float* abuf  = ws + 4 * SZ;
    float* oconv = ws + 5 * SZ;         // 12*64*1024
    float* pos   = ws + 6 * SZ;         // 12*1024*2

    dim3 gg(32, 6, 2);
    dim3 gg2(32, 6, 4);
    gemm_bias_kernel<0><<<gg, 256, 0, stream>>>(Wq, bq, nullptr, nullptr, x, qbuf, nullptr);
    dwconv_kernel<<<768, 256, 0, stream>>>(qbuf, dww, dwb, oconv);
    offset_kernel<<<dim3(12, 4), 256, 0, stream>>>(oconv, lng, lnb, pw, pos);
    sample_kernel<<<3072, 256, 0, stream>>>(x, pos, xs);
    gemm_bias_kernel<1><<<gg2, 256, 0, stream>>>(Wk, bk, Wv, bv, xs, kbuf, vbuf);
    attn_kernel<<<dim3(128, 24), 256, 0, stream>>>(qbuf, kbuf, vbuf, pos, rpe, abuf);
    gemm_bias_kernel<0><<<gg, 256, 0, stream>>>(Wo, bo, nullptr, nullptr, abuf, (float*)d_out, nullptr);
}

// Round 5
// 375.205 us; speedup vs baseline: 1.6562x; 1.3128x over previous
//
#include <hip/hip_runtime.h>
#include <hip/hip_fp16.h>
#include <math.h>

#define HH 32
#define WW 32
#define HWSZ 1024      // H*W
#define CC 384
#define NHEAD 12
#define NGROUP 6
#define HC 32
#define GC 64
#define NS 1024        // n_sample
#define ATTN_SCALE 0.17677669529663687f  // 32^-0.5

// ---------------------------------------------------------------------------
// 1x1-conv GEMM: Y[b,o,n] = sum_c W[o,c] * X[b,c,n] + bias[o]
// M=K=384, N=1024. 64m x 32n tile, BK=32, 4x2 microtile.
// DUAL=1: blockIdx.z = batch*2 + which; which selects (W1,b1,Y1).
// ---------------------------------------------------------------------------
template<int DUAL>
__global__ __launch_bounds__(256, 8) void gemm_bias_kernel(
    const float* __restrict__ W0, const float* __restrict__ bias0,
    const float* __restrict__ W1, const float* __restrict__ bias1,
    const float* __restrict__ X, float* __restrict__ Y0, float* __restrict__ Y1)
{
    int bz, which;
    if (DUAL) { bz = blockIdx.z >> 1; which = blockIdx.z & 1; }
    else      { bz = blockIdx.z;      which = 0; }
    const float* W    = which ? W1 : W0;
    const float* bias = which ? bias1 : bias0;
    float* Y          = which ? Y1 : Y0;

    const float* Xb = X + (size_t)bz * CC * 1024;
    float* Yb = Y + (size_t)bz * CC * 1024;
    const int tm = blockIdx.y * 64;
    const int tn = blockIdx.x * 32;
    const int tid = threadIdx.x;
    const int tx = tid & 15, ty = tid >> 4;

    __shared__ float sW[32][68];   // [k][m]
    __shared__ float sX[32][36];   // [k][n]

    float acc[4][2] = {};

    for (int k0 = 0; k0 < CC; k0 += 32) {
        {   // W tile: 64 m x 32 k, thread loads 8 consecutive k (2 float4)
            int idx = tid * 8;
            int m = idx >> 5;
            int kk = idx & 31;
            float4 wa = *(const float4*)&W[(size_t)(tm + m) * CC + k0 + kk];
            float4 wb = *(const float4*)&W[(size_t)(tm + m) * CC + k0 + kk + 4];
            sW[kk + 0][m] = wa.x; sW[kk + 1][m] = wa.y;
            sW[kk + 2][m] = wa.z; sW[kk + 3][m] = wa.w;
            sW[kk + 4][m] = wb.x; sW[kk + 5][m] = wb.y;
            sW[kk + 6][m] = wb.z; sW[kk + 7][m] = wb.w;
        }
        {   // X tile: 32 k x 32 n, thread loads one float4 along n
            int idx = tid * 4;
            int kk = idx >> 5;
            int n = idx & 31;
            *(float4*)&sX[kk][n] = *(const float4*)&Xb[(size_t)(k0 + kk) * 1024 + tn + n];
        }
        __syncthreads();
#pragma unroll
        for (int kk = 0; kk < 32; ++kk) {
            float a[4];
            *(float4*)a = *(const float4*)&sW[kk][ty * 4];
            float b0 = sX[kk][tx * 2], b1 = sX[kk][tx * 2 + 1];
#pragma unroll
            for (int i = 0; i < 4; ++i) {
                acc[i][0] += a[i] * b0;
                acc[i][1] += a[i] * b1;
            }
        }
        __syncthreads();
    }

#pragma unroll
    for (int i = 0; i < 4; ++i) {
        int m = tm + ty * 4 + i;
        float bv = bias[m];
        float2 r; r.x = acc[i][0] + bv; r.y = acc[i][1] + bv;
        *(float2*)&Yb[(size_t)m * 1024 + tn + tx * 2] = r;
    }
}

// ---------------------------------------------------------------------------
// Depthwise 7x7 conv on q viewed as [12, 64, 32, 32]; zero pad 3.
// ---------------------------------------------------------------------------
__global__ __launch_bounds__(256) void dwconv_kernel(
    const float* __restrict__ q, const float* __restrict__ dww,
    const float* __restrict__ dwb, float* __restrict__ oconv)
{
    const int bc = blockIdx.x;           // 0..767
    const int bg = bc >> 6, c = bc & 63;
    const int b = bg / 6, g = bg % 6;
    const float* plane = q + ((size_t)b * CC + g * 64 + c) * 1024;

    __shared__ float sp[1024];
    __shared__ float sw[49];
    const int tid = threadIdx.x;
    for (int i = tid; i < 1024; i += 256) sp[i] = plane[i];
    if (tid < 49) sw[tid] = dww[c * 49 + tid];
    __syncthreads();

    const float bias = dwb[c];
    for (int i = tid; i < 1024; i += 256) {
        int y = i >> 5, x = i & 31;
        float s = 0.f;
#pragma unroll
        for (int ky = 0; ky < 7; ++ky) {
            int yy = y + ky - 3;
            if (yy < 0 || yy > 31) continue;
#pragma unroll
            for (int kx = 0; kx < 7; ++kx) {
                int xx = x + kx - 3;
                if (xx < 0 || xx > 31) continue;
                s += sp[yy * 32 + xx] * sw[ky * 7 + kx];
            }
        }
        oconv[(size_t)bc * 1024 + i] = s + bias;
    }
}

// ---------------------------------------------------------------------------
// LayerNorm(64 ch) + exact GELU + 1x1->2ch + tanh*2/32 + ref points.
// grid (12, 4); one thread per pixel, channel column held in registers.
// ---------------------------------------------------------------------------
__global__ __launch_bounds__(256) void offset_kernel(
    const float* __restrict__ oconv, const float* __restrict__ lng,
    const float* __restrict__ lnb, const float* __restrict__ pw,
    float* __restrict__ pos)
{
    const int bg = blockIdx.x;
    const int px = blockIdx.y * 256 + threadIdx.x;
    const float* base = oconv + (size_t)bg * 64 * 1024 + px;

    float col[64];
    float sum = 0.f;
#pragma unroll
    for (int c = 0; c < 64; ++c) { col[c] = base[(size_t)c * 1024]; sum += col[c]; }
    float mu = sum * (1.f / 64.f);
    float var = 0.f;
#pragma unroll
    for (int c = 0; c < 64; ++c) { float d = col[c] - mu; var += d * d; }
    float inv = rsqrtf(var * (1.f / 64.f) + 1e-5f);
    float offy = 0.f, offx = 0.f;
#pragma unroll
    for (int c = 0; c < 64; ++c) {
        float v = (col[c] - mu) * inv * lng[c] + lnb[c];
        float g = 0.5f * v * (1.f + erff(v * 0.70710678118654752440f));
        offy += g * pw[c];
        offx += g * pw[64 + c];
    }
    offy = tanhf(offy) * (2.0f / 32.0f);
    offx = tanhf(offx) * (2.0f / 32.0f);
    int y = px >> 5, x = px & 31;
    float ry = ((y + 0.5f) / 32.f) * 2.f - 1.f;
    float rx = ((x + 0.5f) / 32.f) * 2.f - 1.f;
    pos[((size_t)bg * 1024 + px) * 2 + 0] = offy + ry;
    pos[((size_t)bg * 1024 + px) * 2 + 1] = offx + rx;
}

// ---------------------------------------------------------------------------
// Bilinear grid-sample of x at pos (align_corners=True, zeros pad).
// ---------------------------------------------------------------------------
__global__ __launch_bounds__(256) void sample_kernel(
    const float* __restrict__ x, const float* __restrict__ pos,
    float* __restrict__ xs)
{
    const int idx = blockIdx.x * 256 + threadIdx.x;   // 786432 total
    const int s = idx & 1023;
    const int bc = idx >> 10;
    const int c = bc % CC;
    const int b = bc / CC;
    const int bg = b * 6 + (c >> 6);

    float py = pos[((size_t)bg * 1024 + s) * 2 + 0];
    float px = pos[((size_t)bg * 1024 + s) * 2 + 1];
    float gx = (px + 1.f) * 0.5f * 31.f;
    float gy = (py + 1.f) * 0.5f * 31.f;
    float x0f = floorf(gx), y0f = floorf(gy);
    float wx = gx - x0f, wy = gy - y0f;
    int x0 = (int)x0f, y0 = (int)y0f;

    const float* plane = x + (size_t)bc * 1024;
    float acc = 0.f;
    if ((unsigned)x0       <= 31u && (unsigned)y0       <= 31u) acc += plane[y0 * 32 + x0]           * (1.f - wx) * (1.f - wy);
    if ((unsigned)(x0 + 1) <= 31u && (unsigned)y0       <= 31u) acc += plane[y0 * 32 + x0 + 1]       * wx * (1.f - wy);
    if ((unsigned)x0       <= 31u && (unsigned)(y0 + 1) <= 31u) acc += plane[(y0 + 1) * 32 + x0]     * (1.f - wx) * wy;
    if ((unsigned)(x0 + 1) <= 31u && (unsigned)(y0 + 1) <= 31u) acc += plane[(y0 + 1) * 32 + x0 + 1] * wx * wy;
    xs[idx] = acc;
}

// ---------------------------------------------------------------------------
// Attention: block per (bh, 8-query tile). R1 structure (scores->exp->bulk
// store->PV) with fp16 prob buffer (LDS ~17.9KB) and branch-free RPE.
// launch_bounds(256,4): VGPR cap 128 — R4's (256,6) forced scratch spills
// (525MB WRITE_SIZE). Natural usage ~60 VGPR -> 8 waves/SIMD anyway.
// ---------------------------------------------------------------------------
__global__ __launch_bounds__(256, 4) void attn_kernel(
    const float* __restrict__ q, const float* __restrict__ k,
    const float* __restrict__ v, const float* __restrict__ pos,
    const float* __restrict__ rpe, float* __restrict__ out)
{
    const int bh = blockIdx.y;           // 0..23
    const int m0 = blockIdx.x * 8;
    const int b = bh / 12, head = bh % 12;
    const int bg = b * 6 + (head >> 1);
    const int tid = threadIdx.x;
    const int lane = tid & 63, wv = tid >> 6;

    const float* qb = q + ((size_t)b * CC + head * 32) * 1024;
    const float* kb = k + ((size_t)b * CC + head * 32) * 1024;
    const float* vb = v + ((size_t)b * CC + head * 32) * 1024;
    const float* rp = rpe + (size_t)head * (63 * 63);
    const float* pg = pos + (size_t)bg * 1024 * 2;

    __shared__ float sq[32][8];          // [hc][mq]
    __shared__ __half sp[8][1032];       // fp16 unnormalized probs, padded
    __shared__ float rmax[4][8], rsum[4][8];

    {
        int hc = tid >> 3, mq = tid & 7;
        sq[hc][mq] = qb[(size_t)hc * 1024 + m0 + mq];
    }
    __syncthreads();

    // ---- scores: QK^T (keys {tid, tid+256, tid+512, tid+768}) ----
    float sc[8][4];
#pragma unroll
    for (int mq = 0; mq < 8; ++mq)
#pragma unroll
        for (int j = 0; j < 4; ++j) sc[mq][j] = 0.f;

#pragma unroll 4
    for (int hc = 0; hc < 32; ++hc) {
        float qv[8];
#pragma unroll
        for (int mq = 0; mq < 8; ++mq) qv[mq] = sq[hc][mq];
        const float* krow = kb + (size_t)hc * 1024;
#pragma unroll
        for (int j = 0; j < 4; ++j) {
            float kv = krow[tid + j * 256];
#pragma unroll
            for (int mq = 0; mq < 8; ++mq) sc[mq][j] += qv[mq] * kv;
        }
    }

    // ---- query reference points ----
    float qyv[8], qxv[8];
#pragma unroll
    for (int mq = 0; mq < 8; ++mq) {
        int m = m0 + mq;
        qyv[mq] = (((m >> 5) + 0.5f) / 32.f) * 2.f - 1.f;
        qxv[mq] = (((m & 31) + 0.5f) / 32.f) * 2.f - 1.f;
    }

    // ---- scale + RPE bias (branch-free bilinear; gx,gy in (0,62)) ----
#pragma unroll
    for (int j = 0; j < 4; ++j) {
        int n = tid + j * 256;
        float py = pg[n * 2 + 0];
        float px = pg[n * 2 + 1];
#pragma unroll
        for (int mq = 0; mq < 8; ++mq) {
            float gx = (qxv[mq] - px) * 15.5f + 31.f;
            float gy = (qyv[mq] - py) * 15.5f + 31.f;
            float x0f = floorf(gx), y0f = floorf(gy);
            float wx = gx - x0f, wy = gy - y0f;
            int i00 = (int)y0f * 63 + (int)x0f;
            float r00 = rp[i00], r01 = rp[i00 + 1];
            float r10 = rp[i00 + 63], r11 = rp[i00 + 64];
            float top = r00 + (r01 - r00) * wx;
            float bot = r10 + (r11 - r10) * wx;
            sc[mq][j] = sc[mq][j] * ATTN_SCALE + top + (bot - top) * wy;
        }
    }

    // ---- softmax max ----
    float Mv[8];
#pragma unroll
    for (int mq = 0; mq < 8; ++mq) {
        float mv = fmaxf(fmaxf(sc[mq][0], sc[mq][1]), fmaxf(sc[mq][2], sc[mq][3]));
#pragma unroll
        for (int off = 32; off; off >>= 1) mv = fmaxf(mv, __shfl_xor(mv, off));
        if (lane == 0) rmax[wv][mq] = mv;
    }
    __syncthreads();
#pragma unroll
    for (int mq = 0; mq < 8; ++mq)
        Mv[mq] = fmaxf(fmaxf(rmax[0][mq], rmax[1][mq]), fmaxf(rmax[2][mq], rmax[3][mq]));

    // ---- exp, bulk store (fp16), sum ----
#pragma unroll
    for (int mq = 0; mq < 8; ++mq) {
        float s = 0.f;
#pragma unroll
        for (int j = 0; j < 4; ++j) {
            float p = __expf(sc[mq][j] - Mv[mq]);
            sp[mq][tid + j * 256] = __float2half(p);
            s += p;
        }
#pragma unroll
        for (int off = 32; off; off >>= 1) s += __shfl_xor(s, off);
        if (lane == 0) rsum[wv][mq] = s;
    }
    __syncthreads();

    // ---- PV: one (hc, mq) pair per thread, full 1024-key row ----
    {
        const int hcp = tid >> 3, mqp = tid & 7;
        const float invL = 1.f / (rsum[0][mqp] + rsum[1][mqp] + rsum[2][mqp] + rsum[3][mqp]);
        const float* vrow = vb + (size_t)hcp * 1024;
        const __half* prow = sp[mqp];
        float acc0 = 0.f, acc1 = 0.f;
#pragma unroll 4
        for (int i = 0; i < 1024; i += 8) {
            union { uint4 u; __half2 h[4]; } pu;
            pu.u = *(const uint4*)&prow[i];
            float4 va  = *(const float4*)&vrow[i];
            float4 vb2 = *(const float4*)&vrow[i + 4];
            float2 f0 = __half22float2(pu.h[0]);
            float2 f1 = __half22float2(pu.h[1]);
            float2 f2 = __half22float2(pu.h[2]);
            float2 f3 = __half22float2(pu.h[3]);
            acc0 += f0.x * va.x  + f0.y * va.y  + f1.x * va.z  + f1.y * va.w;
            acc1 += f2.x * vb2.x + f2.y * vb2.y + f3.x * vb2.z + f3.y * vb2.w;
        }
        out[((size_t)b * CC + head * 32 + hcp) * 1024 + m0 + mqp] = (acc0 + acc1) * invL;
    }
}

// ---------------------------------------------------------------------------
extern "C" void kernel_launch(void* const* d_in, const int* in_sizes, int n_in,
                              void* d_out, int out_size, void* d_ws, size_t ws_size,
                              hipStream_t stream) {
    const float* x   = (const float*)d_in[0];
    const float* Wq  = (const float*)d_in[1];
    const float* bq  = (const float*)d_in[2];
    const float* Wk  = (const float*)d_in[3];
    const float* bk  = (const float*)d_in[4];
    const float* Wv  = (const float*)d_in[5];
    const float* bv  = (const float*)d_in[6];
    const float* Wo  = (const float*)d_in[7];
    const float* bo  = (const float*)d_in[8];
    const float* dww = (const float*)d_in[9];
    const float* dwb = (const float*)d_in[10];
    const float* lng = (const float*)d_in[11];
    const float* lnb = (const float*)d_in[12];
    const float* pw  = (const float*)d_in[13];
    const float* rpe = (const float*)d_in[14];

    float* ws = (float*)d_ws;
    const size_t SZ = 786432;           // 2*384*1024
    float* qbuf  = ws;
    float* xs    = ws + 1 * SZ;
    float* kbuf  = ws + 2 * SZ;
    float* vbuf  = ws + 3 * SZ;
    float* abuf  = ws + 4 * SZ;
    float* oconv = ws + 5 * SZ;         // 12*64*1024
    float* pos   = ws + 6 * SZ;         // 12*1024*2

    dim3 gg(32, 6, 2);
    dim3 gg2(32, 6, 4);
    gemm_bias_kernel<0><<<gg, 256, 0, stream>>>(Wq, bq, nullptr, nullptr, x, qbuf, nullptr);
    dwconv_kernel<<<768, 256, 0, stream>>>(qbuf, dww, dwb, oconv);
    offset_kernel<<<dim3(12, 4), 256, 0, stream>>>(oconv, lng, lnb, pw, pos);
    sample_kernel<<<3072, 256, 0, stream>>>(x, pos, xs);
    gemm_bias_kernel<1><<<gg2, 256, 0, stream>>>(Wk, bk, Wv, bv, xs, kbuf, vbuf);
    attn_kernel<<<dim3(128, 24), 256, 0, stream>>>(qbuf, kbuf, vbuf, pos, rpe, abuf);
    gemm_bias_kernel<0><<<gg, 256, 0, stream>>>(Wo, bo, nullptr, nullptr, abuf, (float*)d_out, nullptr);
}

// Round 6
// 333.998 us; speedup vs baseline: 1.8605x; 1.1234x over previous
//
#include <hip/hip_runtime.h>
#include <hip/hip_fp16.h>
#include <math.h>

#define HH 32
#define WW 32
#define HWSZ 1024      // H*W
#define CC 384
#define NHEAD 12
#define NGROUP 6
#define HC 32
#define GC 64
#define NS 1024        // n_sample
#define ATTN_SCALE 0.17677669529663687f  // 32^-0.5

// ---------------------------------------------------------------------------
// 1x1-conv GEMM: Y[b,o,n] = sum_c W[o,c] * X[b,c,n] + bias[o]
// M=K=384, N=1024. 64m x 32n tile, BK=32, 4x2 microtile.
// DUAL=1: blockIdx.z = batch*2 + which; which selects (W1,b1,Y1).
// ---------------------------------------------------------------------------
template<int DUAL>
__global__ __launch_bounds__(256, 8) void gemm_bias_kernel(
    const float* __restrict__ W0, const float* __restrict__ bias0,
    const float* __restrict__ W1, const float* __restrict__ bias1,
    const float* __restrict__ X, float* __restrict__ Y0, float* __restrict__ Y1)
{
    int bz, which;
    if (DUAL) { bz = blockIdx.z >> 1; which = blockIdx.z & 1; }
    else      { bz = blockIdx.z;      which = 0; }
    const float* W    = which ? W1 : W0;
    const float* bias = which ? bias1 : bias0;
    float* Y          = which ? Y1 : Y0;

    const float* Xb = X + (size_t)bz * CC * 1024;
    float* Yb = Y + (size_t)bz * CC * 1024;
    const int tm = blockIdx.y * 64;
    const int tn = blockIdx.x * 32;
    const int tid = threadIdx.x;
    const int tx = tid & 15, ty = tid >> 4;

    __shared__ float sW[32][68];   // [k][m]
    __shared__ float sX[32][36];   // [k][n]

    float acc[4][2] = {};

    for (int k0 = 0; k0 < CC; k0 += 32) {
        {   // W tile: 64 m x 32 k, thread loads 8 consecutive k (2 float4)
            int idx = tid * 8;
            int m = idx >> 5;
            int kk = idx & 31;
            float4 wa = *(const float4*)&W[(size_t)(tm + m) * CC + k0 + kk];
            float4 wb = *(const float4*)&W[(size_t)(tm + m) * CC + k0 + kk + 4];
            sW[kk + 0][m] = wa.x; sW[kk + 1][m] = wa.y;
            sW[kk + 2][m] = wa.z; sW[kk + 3][m] = wa.w;
            sW[kk + 4][m] = wb.x; sW[kk + 5][m] = wb.y;
            sW[kk + 6][m] = wb.z; sW[kk + 7][m] = wb.w;
        }
        {   // X tile: 32 k x 32 n, thread loads one float4 along n
            int idx = tid * 4;
            int kk = idx >> 5;
            int n = idx & 31;
            *(float4*)&sX[kk][n] = *(const float4*)&Xb[(size_t)(k0 + kk) * 1024 + tn + n];
        }
        __syncthreads();
#pragma unroll
        for (int kk = 0; kk < 32; ++kk) {
            float a[4];
            *(float4*)a = *(const float4*)&sW[kk][ty * 4];
            float b0 = sX[kk][tx * 2], b1 = sX[kk][tx * 2 + 1];
#pragma unroll
            for (int i = 0; i < 4; ++i) {
                acc[i][0] += a[i] * b0;
                acc[i][1] += a[i] * b1;
            }
        }
        __syncthreads();
    }

#pragma unroll
    for (int i = 0; i < 4; ++i) {
        int m = tm + ty * 4 + i;
        float bv = bias[m];
        float2 r; r.x = acc[i][0] + bv; r.y = acc[i][1] + bv;
        *(float2*)&Yb[(size_t)m * 1024 + tn + tx * 2] = r;
    }
}

// ---------------------------------------------------------------------------
// Depthwise 7x7 conv on q viewed as [12, 64, 32, 32]; zero pad 3.
// ---------------------------------------------------------------------------
__global__ __launch_bounds__(256) void dwconv_kernel(
    const float* __restrict__ q, const float* __restrict__ dww,
    const float* __restrict__ dwb, float* __restrict__ oconv)
{
    const int bc = blockIdx.x;           // 0..767
    const int bg = bc >> 6, c = bc & 63;
    const int b = bg / 6, g = bg % 6;
    const float* plane = q + ((size_t)b * CC + g * 64 + c) * 1024;

    __shared__ float sp[1024];
    __shared__ float sw[49];
    const int tid = threadIdx.x;
    for (int i = tid; i < 1024; i += 256) sp[i] = plane[i];
    if (tid < 49) sw[tid] = dww[c * 49 + tid];
    __syncthreads();

    const float bias = dwb[c];
    for (int i = tid; i < 1024; i += 256) {
        int y = i >> 5, x = i & 31;
        float s = 0.f;
#pragma unroll
        for (int ky = 0; ky < 7; ++ky) {
            int yy = y + ky - 3;
            if (yy < 0 || yy > 31) continue;
#pragma unroll
            for (int kx = 0; kx < 7; ++kx) {
                int xx = x + kx - 3;
                if (xx < 0 || xx > 31) continue;
                s += sp[yy * 32 + xx] * sw[ky * 7 + kx];
            }
        }
        oconv[(size_t)bc * 1024 + i] = s + bias;
    }
}

// ---------------------------------------------------------------------------
// LayerNorm(64 ch) + exact GELU + 1x1->2ch + tanh*2/32 + ref points.
// grid (12, 4); one thread per pixel, channel column held in registers.
// ---------------------------------------------------------------------------
__global__ __launch_bounds__(256) void offset_kernel(
    const float* __restrict__ oconv, const float* __restrict__ lng,
    const float* __restrict__ lnb, const float* __restrict__ pw,
    float* __restrict__ pos)
{
    const int bg = blockIdx.x;
    const int px = blockIdx.y * 256 + threadIdx.x;
    const float* base = oconv + (size_t)bg * 64 * 1024 + px;

    float col[64];
    float sum = 0.f;
#pragma unroll
    for (int c = 0; c < 64; ++c) { col[c] = base[(size_t)c * 1024]; sum += col[c]; }
    float mu = sum * (1.f / 64.f);
    float var = 0.f;
#pragma unroll
    for (int c = 0; c < 64; ++c) { float d = col[c] - mu; var += d * d; }
    float inv = rsqrtf(var * (1.f / 64.f) + 1e-5f);
    float offy = 0.f, offx = 0.f;
#pragma unroll
    for (int c = 0; c < 64; ++c) {
        float v = (col[c] - mu) * inv * lng[c] + lnb[c];
        float g = 0.5f * v * (1.f + erff(v * 0.70710678118654752440f));
        offy += g * pw[c];
        offx += g * pw[64 + c];
    }
    offy = tanhf(offy) * (2.0f / 32.0f);
    offx = tanhf(offx) * (2.0f / 32.0f);
    int y = px >> 5, x = px & 31;
    float ry = ((y + 0.5f) / 32.f) * 2.f - 1.f;
    float rx = ((x + 0.5f) / 32.f) * 2.f - 1.f;
    pos[((size_t)bg * 1024 + px) * 2 + 0] = offy + ry;
    pos[((size_t)bg * 1024 + px) * 2 + 1] = offx + rx;
}

// ---------------------------------------------------------------------------
// Bilinear grid-sample of x at pos (align_corners=True, zeros pad).
// ---------------------------------------------------------------------------
__global__ __launch_bounds__(256) void sample_kernel(
    const float* __restrict__ x, const float* __restrict__ pos,
    float* __restrict__ xs)
{
    const int idx = blockIdx.x * 256 + threadIdx.x;   // 786432 total
    const int s = idx & 1023;
    const int bc = idx >> 10;
    const int c = bc % CC;
    const int b = bc / CC;
    const int bg = b * 6 + (c >> 6);

    float py = pos[((size_t)bg * 1024 + s) * 2 + 0];
    float px = pos[((size_t)bg * 1024 + s) * 2 + 1];
    float gx = (px + 1.f) * 0.5f * 31.f;
    float gy = (py + 1.f) * 0.5f * 31.f;
    float x0f = floorf(gx), y0f = floorf(gy);
    float wx = gx - x0f, wy = gy - y0f;
    int x0 = (int)x0f, y0 = (int)y0f;

    const float* plane = x + (size_t)bc * 1024;
    float acc = 0.f;
    if ((unsigned)x0       <= 31u && (unsigned)y0       <= 31u) acc += plane[y0 * 32 + x0]           * (1.f - wx) * (1.f - wy);
    if ((unsigned)(x0 + 1) <= 31u && (unsigned)y0       <= 31u) acc += plane[y0 * 32 + x0 + 1]       * wx * (1.f - wy);
    if ((unsigned)x0       <= 31u && (unsigned)(y0 + 1) <= 31u) acc += plane[(y0 + 1) * 32 + x0]     * (1.f - wx) * wy;
    if ((unsigned)(x0 + 1) <= 31u && (unsigned)(y0 + 1) <= 31u) acc += plane[(y0 + 1) * 32 + x0 + 1] * wx * wy;
    xs[idx] = acc;
}

// ---------------------------------------------------------------------------
// Attention: block per (bh, 8-query tile). RPE head table staged in LDS
// (15.9KB) so the bilinear lookups are ds_reads — no global-load hoisting,
// no VGPR blowup/spill (R4/R5 lesson). fp16 prob buffer (16.5KB).
// No waves bound: let the allocator pick (R1: 56 VGPR, no spill).
// ---------------------------------------------------------------------------
__global__ __launch_bounds__(256) void attn_kernel(
    const float* __restrict__ q, const float* __restrict__ k,
    const float* __restrict__ v, const float* __restrict__ pos,
    const float* __restrict__ rpe, float* __restrict__ out)
{
    const int bh = blockIdx.y;           // 0..23
    const int m0 = blockIdx.x * 8;
    const int b = bh / 12, head = bh % 12;
    const int bg = b * 6 + (head >> 1);
    const int tid = threadIdx.x;
    const int lane = tid & 63, wv = tid >> 6;

    const float* qb = q + ((size_t)b * CC + head * 32) * 1024;
    const float* kb = k + ((size_t)b * CC + head * 32) * 1024;
    const float* vb = v + ((size_t)b * CC + head * 32) * 1024;
    const float* rp = rpe + (size_t)head * (63 * 63);
    const float* pg = pos + (size_t)bg * 1024 * 2;

    __shared__ float sq[32][8];          // [hc][mq]
    __shared__ __half sp[8][1032];       // fp16 unnormalized probs, padded
    __shared__ float srpe[63 * 63];      // per-head RPE table (15.9KB)
    __shared__ float rmax[4][8], rsum[4][8];

    {
        int hc = tid >> 3, mq = tid & 7;
        sq[hc][mq] = qb[(size_t)hc * 1024 + m0 + mq];
    }
    for (int i = tid; i < 63 * 63; i += 256) srpe[i] = rp[i];
    __syncthreads();

    // ---- scores: QK^T (keys {tid, tid+256, tid+512, tid+768}) ----
    float sc[8][4];
#pragma unroll
    for (int mq = 0; mq < 8; ++mq)
#pragma unroll
        for (int j = 0; j < 4; ++j) sc[mq][j] = 0.f;

#pragma unroll 4
    for (int hc = 0; hc < 32; ++hc) {
        float qv[8];
#pragma unroll
        for (int mq = 0; mq < 8; ++mq) qv[mq] = sq[hc][mq];
        const float* krow = kb + (size_t)hc * 1024;
#pragma unroll
        for (int j = 0; j < 4; ++j) {
            float kv = krow[tid + j * 256];
#pragma unroll
            for (int mq = 0; mq < 8; ++mq) sc[mq][j] += qv[mq] * kv;
        }
    }

    // ---- query reference points ----
    float qyv[8], qxv[8];
#pragma unroll
    for (int mq = 0; mq < 8; ++mq) {
        int m = m0 + mq;
        qyv[mq] = (((m >> 5) + 0.5f) / 32.f) * 2.f - 1.f;
        qxv[mq] = (((m & 31) + 0.5f) / 32.f) * 2.f - 1.f;
    }

    // ---- scale + RPE bias from LDS (branch-free; gx,gy in (0,62)) ----
#pragma unroll
    for (int j = 0; j < 4; ++j) {
        int n = tid + j * 256;
        float py = pg[n * 2 + 0];
        float px = pg[n * 2 + 1];
#pragma unroll
        for (int mq = 0; mq < 8; ++mq) {
            float gx = (qxv[mq] - px) * 15.5f + 31.f;
            float gy = (qyv[mq] - py) * 15.5f + 31.f;
            float x0f = floorf(gx), y0f = floorf(gy);
            float wx = gx - x0f, wy = gy - y0f;
            int i00 = (int)y0f * 63 + (int)x0f;
            float r00 = srpe[i00], r01 = srpe[i00 + 1];
            float r10 = srpe[i00 + 63], r11 = srpe[i00 + 64];
            float top = r00 + (r01 - r00) * wx;
            float bot = r10 + (r11 - r10) * wx;
            sc[mq][j] = sc[mq][j] * ATTN_SCALE + top + (bot - top) * wy;
        }
    }

    // ---- softmax max ----
    float Mv[8];
#pragma unroll
    for (int mq = 0; mq < 8; ++mq) {
        float mv = fmaxf(fmaxf(sc[mq][0], sc[mq][1]), fmaxf(sc[mq][2], sc[mq][3]));
#pragma unroll
        for (int off = 32; off; off >>= 1) mv = fmaxf(mv, __shfl_xor(mv, off));
        if (lane == 0) rmax[wv][mq] = mv;
    }
    __syncthreads();
#pragma unroll
    for (int mq = 0; mq < 8; ++mq)
        Mv[mq] = fmaxf(fmaxf(rmax[0][mq], rmax[1][mq]), fmaxf(rmax[2][mq], rmax[3][mq]));

    // ---- exp, bulk store (fp16), sum ----
#pragma unroll
    for (int mq = 0; mq < 8; ++mq) {
        float s = 0.f;
#pragma unroll
        for (int j = 0; j < 4; ++j) {
            float p = __expf(sc[mq][j] - Mv[mq]);
            sp[mq][tid + j * 256] = __float2half(p);
            s += p;
        }
#pragma unroll
        for (int off = 32; off; off >>= 1) s += __shfl_xor(s, off);
        if (lane == 0) rsum[wv][mq] = s;
    }
    __syncthreads();

    // ---- PV: one (hc, mq) pair per thread, full 1024-key row ----
    {
        const int hcp = tid >> 3, mqp = tid & 7;
        const float invL = 1.f / (rsum[0][mqp] + rsum[1][mqp] + rsum[2][mqp] + rsum[3][mqp]);
        const float* vrow = vb + (size_t)hcp * 1024;
        const __half* prow = sp[mqp];
        float acc0 = 0.f, acc1 = 0.f;
#pragma unroll 4
        for (int i = 0; i < 1024; i += 8) {
            union { uint4 u; __half2 h[4]; } pu;
            pu.u = *(const uint4*)&prow[i];
            float4 va  = *(const float4*)&vrow[i];
            float4 vb2 = *(const float4*)&vrow[i + 4];
            float2 f0 = __half22float2(pu.h[0]);
            float2 f1 = __half22float2(pu.h[1]);
            float2 f2 = __half22float2(pu.h[2]);
            float2 f3 = __half22float2(pu.h[3]);
            acc0 += f0.x * va.x  + f0.y * va.y  + f1.x * va.z  + f1.y * va.w;
            acc1 += f2.x * vb2.x + f2.y * vb2.y + f3.x * vb2.z + f3.y * vb2.w;
        }
        out[((size_t)b * CC + head * 32 + hcp) * 1024 + m0 + mqp] = (acc0 + acc1) * invL;
    }
}

// ---------------------------------------------------------------------------
extern "C" void kernel_launch(void* const* d_in, const int* in_sizes, int n_in,
                              void* d_out, int out_size, void* d_ws, size_t ws_size,
                              hipStream_t stream) {
    const float* x   = (const float*)d_in[0];
    const float* Wq  = (const float*)d_in[1];
    const float* bq  = (const float*)d_in[2];
    const float* Wk  = (const float*)d_in[3];
    const float* bk  = (const float*)d_in[4];
    const float* Wv  = (const float*)d_in[5];
    const float* bv  = (const float*)d_in[6];
    const float* Wo  = (const float*)d_in[7];
    const float* bo  = (const float*)d_in[8];
    const float* dww = (const float*)d_in[9];
    const float* dwb = (const float*)d_in[10];
    const float* lng = (const float*)d_in[11];
    const float* lnb = (const float*)d_in[12];
    const float* pw  = (const float*)d_in[13];
    const float* rpe = (const float*)d_in[14];

    float* ws = (float*)d_ws;
    const size_t SZ = 786432;           // 2*384*1024
    float* qbuf  = ws;
    float* xs    = ws + 1 * SZ;
    float* kbuf  = ws + 2 * SZ;
    float* vbuf  = ws + 3 * SZ;
    float* abuf  = ws + 4 * SZ;
    float* oconv = ws + 5 * SZ;         // 12*64*1024
    float* pos   = ws + 6 * SZ;         // 12*1024*2

    dim3 gg(32, 6, 2);
    dim3 gg2(32, 6, 4);
    gemm_bias_kernel<0><<<gg, 256, 0, stream>>>(Wq, bq, nullptr, nullptr, x, qbuf, nullptr);
    dwconv_kernel<<<768, 256, 0, stream>>>(qbuf, dww, dwb, oconv);
    offset_kernel<<<dim3(12, 4), 256, 0, stream>>>(oconv, lng, lnb, pw, pos);
    sample_kernel<<<3072, 256, 0, stream>>>(x, pos, xs);
    gemm_bias_kernel<1><<<gg2, 256, 0, stream>>>(Wk, bk, Wv, bv, xs, kbuf, vbuf);
    attn_kernel<<<dim3(128, 24), 256, 0, stream>>>(qbuf, kbuf, vbuf, pos, rpe, abuf);
    gemm_bias_kernel<0><<<gg, 256, 0, stream>>>(Wo, bo, nullptr, nullptr, abuf, (float*)d_out, nullptr);
}

// Round 7
// 284.826 us; speedup vs baseline: 2.1817x; 1.1726x over previous
//
#include <hip/hip_runtime.h>
#include <hip/hip_fp16.h>
#include <math.h>

#define HH 32
#define WW 32
#define HWSZ 1024      // H*W
#define CC 384
#define NHEAD 12
#define NGROUP 6
#define HC 32
#define GC 64
#define NS 1024        // n_sample
#define ATTN_SCALE 0.17677669529663687f  // 32^-0.5

typedef _Float16 half8_t __attribute__((ext_vector_type(8)));
typedef _Float16 half4_t __attribute__((ext_vector_type(4)));
typedef _Float16 half2_t __attribute__((ext_vector_type(2)));
typedef float    f4_t    __attribute__((ext_vector_type(4)));

// ---------------------------------------------------------------------------
// 1x1-conv GEMM (fp32 out): Y[b,o,n] = sum_c W[o,c] X[b,c,n] + bias[o]
// 64m x 32n tile, BK=32, 4x2 microtile. Used for q and o projections.
// ---------------------------------------------------------------------------
template<int DUAL>
__global__ __launch_bounds__(256, 8) void gemm_bias_kernel(
    const float* __restrict__ W0, const float* __restrict__ bias0,
    const float* __restrict__ W1, const float* __restrict__ bias1,
    const float* __restrict__ X, float* __restrict__ Y0, float* __restrict__ Y1)
{
    int bz, which;
    if (DUAL) { bz = blockIdx.z >> 1; which = blockIdx.z & 1; }
    else      { bz = blockIdx.z;      which = 0; }
    const float* W    = which ? W1 : W0;
    const float* bias = which ? bias1 : bias0;
    float* Y          = which ? Y1 : Y0;

    const float* Xb = X + (size_t)bz * CC * 1024;
    float* Yb = Y + (size_t)bz * CC * 1024;
    const int tm = blockIdx.y * 64;
    const int tn = blockIdx.x * 32;
    const int tid = threadIdx.x;
    const int tx = tid & 15, ty = tid >> 4;

    __shared__ float sW[32][68];
    __shared__ float sX[32][36];

    float acc[4][2] = {};

    for (int k0 = 0; k0 < CC; k0 += 32) {
        {
            int idx = tid * 8;
            int m = idx >> 5;
            int kk = idx & 31;
            float4 wa = *(const float4*)&W[(size_t)(tm + m) * CC + k0 + kk];
            float4 wb = *(const float4*)&W[(size_t)(tm + m) * CC + k0 + kk + 4];
            sW[kk + 0][m] = wa.x; sW[kk + 1][m] = wa.y;
            sW[kk + 2][m] = wa.z; sW[kk + 3][m] = wa.w;
            sW[kk + 4][m] = wb.x; sW[kk + 5][m] = wb.y;
            sW[kk + 6][m] = wb.z; sW[kk + 7][m] = wb.w;
        }
        {
            int idx = tid * 4;
            int kk = idx >> 5;
            int n = idx & 31;
            *(float4*)&sX[kk][n] = *(const float4*)&Xb[(size_t)(k0 + kk) * 1024 + tn + n];
        }
        __syncthreads();
#pragma unroll
        for (int kk = 0; kk < 32; ++kk) {
            float a[4];
            *(float4*)a = *(const float4*)&sW[kk][ty * 4];
            float b0 = sX[kk][tx * 2], b1 = sX[kk][tx * 2 + 1];
#pragma unroll
            for (int i = 0; i < 4; ++i) {
                acc[i][0] += a[i] * b0;
                acc[i][1] += a[i] * b1;
            }
        }
        __syncthreads();
    }

#pragma unroll
    for (int i = 0; i < 4; ++i) {
        int m = tm + ty * 4 + i;
        float bv = bias[m];
        float2 r; r.x = acc[i][0] + bv; r.y = acc[i][1] + bv;
        *(float2*)&Yb[(size_t)m * 1024 + tn + tx * 2] = r;
    }
}

// ---------------------------------------------------------------------------
// K/V projection GEMM: same tiling, epilogue emits f16 hi/lo splits in
// MFMA-B-frag-friendly layouts:
//   K: khT/klT [bh][n=1024][hc=32]  (B-frag for QK: contiguous hc)
//   V: vh/vl   [bh][hc=32][n=1024]  (B-frag for PV: contiguous n)
// ---------------------------------------------------------------------------
__global__ __launch_bounds__(256, 8) void gemm_kv_kernel(
    const float* __restrict__ Wk, const float* __restrict__ bk,
    const float* __restrict__ Wv, const float* __restrict__ bv,
    const float* __restrict__ X,
    _Float16* __restrict__ khT, _Float16* __restrict__ klT,
    _Float16* __restrict__ vhb, _Float16* __restrict__ vlb)
{
    const int bz = blockIdx.z >> 1, which = blockIdx.z & 1;
    const float* W    = which ? Wv : Wk;
    const float* bias = which ? bv : bk;

    const float* Xb = X + (size_t)bz * CC * 1024;
    const int tm = blockIdx.y * 64;
    const int tn = blockIdx.x * 32;
    const int tid = threadIdx.x;
    const int tx = tid & 15, ty = tid >> 4;

    __shared__ float sW[32][68];
    __shared__ float sX[32][36];

    float acc[4][2] = {};

    for (int k0 = 0; k0 < CC; k0 += 32) {
        {
            int idx = tid * 8;
            int m = idx >> 5;
            int kk = idx & 31;
            float4 wa = *(const float4*)&W[(size_t)(tm + m) * CC + k0 + kk];
            float4 wb = *(const float4*)&W[(size_t)(tm + m) * CC + k0 + kk + 4];
            sW[kk + 0][m] = wa.x; sW[kk + 1][m] = wa.y;
            sW[kk + 2][m] = wa.z; sW[kk + 3][m] = wa.w;
            sW[kk + 4][m] = wb.x; sW[kk + 5][m] = wb.y;
            sW[kk + 6][m] = wb.z; sW[kk + 7][m] = wb.w;
        }
        {
            int idx = tid * 4;
            int kk = idx >> 5;
            int n = idx & 31;
            *(float4*)&sX[kk][n] = *(const float4*)&Xb[(size_t)(k0 + kk) * 1024 + tn + n];
        }
        __syncthreads();
#pragma unroll
        for (int kk = 0; kk < 32; ++kk) {
            float a[4];
            *(float4*)a = *(const float4*)&sW[kk][ty * 4];
            float b0 = sX[kk][tx * 2], b1 = sX[kk][tx * 2 + 1];
#pragma unroll
            for (int i = 0; i < 4; ++i) {
                acc[i][0] += a[i] * b0;
                acc[i][1] += a[i] * b1;
            }
        }
        __syncthreads();
    }

    const int ch0 = tm + ty * 4;
    const int head = ch0 >> 5, hc0 = ch0 & 31;   // 4-row group never crosses head
    const int bhh = bz * 12 + head;
    float bvs[4];
#pragma unroll
    for (int i = 0; i < 4; ++i) bvs[i] = bias[ch0 + i];

    if (which == 0) {   // K -> [n][hc] layout
#pragma unroll
        for (int j = 0; j < 2; ++j) {
            int n = tn + tx * 2 + j;
            half4_t hh, ll;
#pragma unroll
            for (int i = 0; i < 4; ++i) {
                float val = acc[i][j] + bvs[i];
                _Float16 h = (_Float16)val;
                hh[i] = h; ll[i] = (_Float16)(val - (float)h);
            }
            size_t base = ((size_t)bhh * 1024 + n) * 32 + hc0;
            *(half4_t*)&khT[base] = hh;
            *(half4_t*)&klT[base] = ll;
        }
    } else {            // V -> [hc][n] layout
#pragma unroll
        for (int i = 0; i < 4; ++i) {
            half2_t hh, ll;
#pragma unroll
            for (int j = 0; j < 2; ++j) {
                float val = acc[i][j] + bvs[i];
                _Float16 h = (_Float16)val;
                hh[j] = h; ll[j] = (_Float16)(val - (float)h);
            }
            size_t base = ((size_t)bhh * 32 + hc0 + i) * 1024 + tn + tx * 2;
            *(half2_t*)&vhb[base] = hh;
            *(half2_t*)&vlb[base] = ll;
        }
    }
}

// ---------------------------------------------------------------------------
// Depthwise 7x7 conv on q viewed as [12, 64, 32, 32]; zero pad 3.
// ---------------------------------------------------------------------------
__global__ __launch_bounds__(256) void dwconv_kernel(
    const float* __restrict__ q, const float* __restrict__ dww,
    const float* __restrict__ dwb, float* __restrict__ oconv)
{
    const int bc = blockIdx.x;
    const int bg = bc >> 6, c = bc & 63;
    const int b = bg / 6, g = bg % 6;
    const float* plane = q + ((size_t)b * CC + g * 64 + c) * 1024;

    __shared__ float sp[1024];
    __shared__ float sw[49];
    const int tid = threadIdx.x;
    for (int i = tid; i < 1024; i += 256) sp[i] = plane[i];
    if (tid < 49) sw[tid] = dww[c * 49 + tid];
    __syncthreads();

    const float bias = dwb[c];
    for (int i = tid; i < 1024; i += 256) {
        int y = i >> 5, x = i & 31;
        float s = 0.f;
#pragma unroll
        for (int ky = 0; ky < 7; ++ky) {
            int yy = y + ky - 3;
            if (yy < 0 || yy > 31) continue;
#pragma unroll
            for (int kx = 0; kx < 7; ++kx) {
                int xx = x + kx - 3;
                if (xx < 0 || xx > 31) continue;
                s += sp[yy * 32 + xx] * sw[ky * 7 + kx];
            }
        }
        oconv[(size_t)bc * 1024 + i] = s + bias;
    }
}

// ---------------------------------------------------------------------------
// LayerNorm(64 ch) + exact GELU + 1x1->2ch + tanh*2/32 + ref points.
// ---------------------------------------------------------------------------
__global__ __launch_bounds__(256) void offset_kernel(
    const float* __restrict__ oconv, const float* __restrict__ lng,
    const float* __restrict__ lnb, const float* __restrict__ pw,
    float* __restrict__ pos)
{
    const int bg = blockIdx.x;
    const int px = blockIdx.y * 256 + threadIdx.x;
    const float* base = oconv + (size_t)bg * 64 * 1024 + px;

    float col[64];
    float sum = 0.f;
#pragma unroll
    for (int c = 0; c < 64; ++c) { col[c] = base[(size_t)c * 1024]; sum += col[c]; }
    float mu = sum * (1.f / 64.f);
    float var = 0.f;
#pragma unroll
    for (int c = 0; c < 64; ++c) { float d = col[c] - mu; var += d * d; }
    float inv = rsqrtf(var * (1.f / 64.f) + 1e-5f);
    float offy = 0.f, offx = 0.f;
#pragma unroll
    for (int c = 0; c < 64; ++c) {
        float v = (col[c] - mu) * inv * lng[c] + lnb[c];
        float g = 0.5f * v * (1.f + erff(v * 0.70710678118654752440f));
        offy += g * pw[c];
        offx += g * pw[64 + c];
    }
    offy = tanhf(offy) * (2.0f / 32.0f);
    offx = tanhf(offx) * (2.0f / 32.0f);
    int y = px >> 5, x = px & 31;
    float ry = ((y + 0.5f) / 32.f) * 2.f - 1.f;
    float rx = ((x + 0.5f) / 32.f) * 2.f - 1.f;
    pos[((size_t)bg * 1024 + px) * 2 + 0] = offy + ry;
    pos[((size_t)bg * 1024 + px) * 2 + 1] = offx + rx;
}

// ---------------------------------------------------------------------------
// Bilinear grid-sample of x at pos (align_corners=True, zeros pad).
// ---------------------------------------------------------------------------
__global__ __launch_bounds__(256) void sample_kernel(
    const float* __restrict__ x, const float* __restrict__ pos,
    float* __restrict__ xs)
{
    const int idx = blockIdx.x * 256 + threadIdx.x;
    const int s = idx & 1023;
    const int bc = idx >> 10;
    const int c = bc % CC;
    const int b = bc / CC;
    const int bg = b * 6 + (c >> 6);

    float py = pos[((size_t)bg * 1024 + s) * 2 + 0];
    float px = pos[((size_t)bg * 1024 + s) * 2 + 1];
    float gx = (px + 1.f) * 0.5f * 31.f;
    float gy = (py + 1.f) * 0.5f * 31.f;
    float x0f = floorf(gx), y0f = floorf(gy);
    float wx = gx - x0f, wy = gy - y0f;
    int x0 = (int)x0f, y0 = (int)y0f;

    const float* plane = x + (size_t)bc * 1024;
    float acc = 0.f;
    if ((unsigned)x0       <= 31u && (unsigned)y0       <= 31u) acc += plane[y0 * 32 + x0]           * (1.f - wx) * (1.f - wy);
    if ((unsigned)(x0 + 1) <= 31u && (unsigned)y0       <= 31u) acc += plane[y0 * 32 + x0 + 1]       * wx * (1.f - wy);
    if ((unsigned)x0       <= 31u && (unsigned)(y0 + 1) <= 31u) acc += plane[(y0 + 1) * 32 + x0]     * (1.f - wx) * wy;
    if ((unsigned)(x0 + 1) <= 31u && (unsigned)(y0 + 1) <= 31u) acc += plane[(y0 + 1) * 32 + x0 + 1] * wx * wy;
    xs[idx] = acc;
}

// ---------------------------------------------------------------------------
// MFMA flash attention. Block = 128 thr (2 waves); wave = 16 queries x 1024
// keys via 16x16x32 f16 MFMA, 64-key chunks, online softmax.
// QK: qh*kh + qh*kl + ql*kh (f16 hi/lo split ~ fp32 exact).
// PV: P(f16) * (Vh + Vl).  P transposed C->A layout via wave-private LDS.
// Fragment layouts (gfx950 16x16x32): A[m=lane&15][k=quad*8+j],
// B[k=quad*8+j][n=lane&15], C/D[row=quad*4+reg][col=lane&15].
// ---------------------------------------------------------------------------
__global__ __launch_bounds__(128) void attn_mfma_kernel(
    const float* __restrict__ q, const _Float16* __restrict__ khT,
    const _Float16* __restrict__ klT, const _Float16* __restrict__ vhb,
    const _Float16* __restrict__ vlb, const float* __restrict__ pos,
    const float* __restrict__ rpe, float* __restrict__ out)
{
    const int bh = blockIdx.y;
    const int b = bh / 12, head = bh % 12;
    const int bg = b * 6 + (head >> 1);
    const int mblk = blockIdx.x * 32;
    const int tid = threadIdx.x;
    const int w = tid >> 6, lane = tid & 63;
    const int quad = lane >> 4, lcol = lane & 15;

    __shared__ _Float16 srpe[63 * 63 + 1];   // 7.9KB, f16 RPE table
    __shared__ float sq[32 * 36];            // 4.6KB, padded q tile [m][hc]
    __shared__ _Float16 sp[2][16 * 72];      // 4.6KB, per-wave P transpose buf

    const float* rp = rpe + (size_t)head * 3969;
    for (int i = tid; i < 3969; i += 128) srpe[i] = (_Float16)rp[i];
    {
        const float* qb = q + ((size_t)b * CC + head * 32) * 1024 + mblk;
#pragma unroll
        for (int i = 0; i < 8; ++i) {
            int idx = i * 128 + tid;
            int hc = idx >> 5, m = idx & 31;
            sq[m * 36 + hc] = qb[(size_t)hc * 1024 + m];
        }
    }
    __syncthreads();

    // Q A-fragments, f16 hi/lo
    half8_t qh, ql;
    {
        const float* qrow = &sq[(w * 16 + lcol) * 36 + quad * 8];
#pragma unroll
        for (int j = 0; j < 8; ++j) {
            float v = qrow[j];
            _Float16 h = (_Float16)v;
            qh[j] = h; ql[j] = (_Float16)(v - (float)h);
        }
    }

    const int mwave = mblk + w * 16;
    const float qyw = (((mwave >> 5) + 0.5f) * (1.f / 32.f)) * 2.f - 1.f;
    float qxr[4];
#pragma unroll
    for (int r = 0; r < 4; ++r)
        qxr[r] = (((mwave & 31) + quad * 4 + r + 0.5f) * (1.f / 32.f)) * 2.f - 1.f;

    const float2* pgv = (const float2*)(pos + (size_t)bg * 2048);
    const _Float16* khb = khT + (size_t)bh * 1024 * 32;
    const _Float16* klb = klT + (size_t)bh * 1024 * 32;
    const _Float16* vhh = vhb + (size_t)bh * 32 * 1024;
    const _Float16* vll = vlb + (size_t)bh * 32 * 1024;
    _Float16* spw = sp[w];

    f4_t o0 = {0.f, 0.f, 0.f, 0.f}, o1 = {0.f, 0.f, 0.f, 0.f};
    float mrow[4] = {-3.0e38f, -3.0e38f, -3.0e38f, -3.0e38f};
    float lrow[4] = {0.f, 0.f, 0.f, 0.f};

    for (int n0 = 0; n0 < 1024; n0 += 64) {
        f4_t S[4];
#pragma unroll
        for (int t = 0; t < 4; ++t) {
            int key = n0 + t * 16 + lcol;
            half8_t kh = *(const half8_t*)&khb[(size_t)key * 32 + quad * 8];
            half8_t kl = *(const half8_t*)&klb[(size_t)key * 32 + quad * 8];
            f4_t s = {0.f, 0.f, 0.f, 0.f};
            s = __builtin_amdgcn_mfma_f32_16x16x32_f16(ql, kh, s, 0, 0, 0);
            s = __builtin_amdgcn_mfma_f32_16x16x32_f16(qh, kl, s, 0, 0, 0);
            s = __builtin_amdgcn_mfma_f32_16x16x32_f16(qh, kh, s, 0, 0, 0);
            // RPE bias (gy shared across the 4 rows; taps from f16 LDS table)
            float2 pp = pgv[key];
            float gy = (qyw - pp.x) * 15.5f + 31.f;
            float y0f = floorf(gy);
            float wy = gy - y0f;
            int ybase = (int)y0f * 63;
#pragma unroll
            for (int r = 0; r < 4; ++r) {
                float gx = (qxr[r] - pp.y) * 15.5f + 31.f;
                float x0f = floorf(gx);
                float wx = gx - x0f;
                int i00 = ybase + (int)x0f;
                float r00 = (float)srpe[i00],      r01 = (float)srpe[i00 + 1];
                float r10 = (float)srpe[i00 + 63], r11 = (float)srpe[i00 + 64];
                float top = r00 + (r01 - r00) * wx;
                float bot = r10 + (r11 - r10) * wx;
                s[r] = s[r] * ATTN_SCALE + top + (bot - top) * wy;
            }
            S[t] = s;
        }

        // online softmax (per-row state; rows live in quad, cols in 16 lanes)
#pragma unroll
        for (int r = 0; r < 4; ++r) {
            float cm = fmaxf(fmaxf(S[0][r], S[1][r]), fmaxf(S[2][r], S[3][r]));
            cm = fmaxf(cm, __shfl_xor(cm, 1));
            cm = fmaxf(cm, __shfl_xor(cm, 2));
            cm = fmaxf(cm, __shfl_xor(cm, 4));
            cm = fmaxf(cm, __shfl_xor(cm, 8));
            float mnew = fmaxf(mrow[r], cm);
            float alpha = __expf(mrow[r] - mnew);
            mrow[r] = mnew;
            lrow[r] *= alpha;
            o0[r] *= alpha;
            o1[r] *= alpha;
        }
        float rs[4] = {0.f, 0.f, 0.f, 0.f};
#pragma unroll
        for (int t = 0; t < 4; ++t) {
#pragma unroll
            for (int r = 0; r < 4; ++r) {
                float p = __expf(S[t][r] - mrow[r]);
                rs[r] += p;
                spw[(quad * 4 + r) * 72 + t * 16 + lcol] = (_Float16)p;
            }
        }
#pragma unroll
        for (int r = 0; r < 4; ++r) {
            float s = rs[r];
            s += __shfl_xor(s, 1); s += __shfl_xor(s, 2);
            s += __shfl_xor(s, 4); s += __shfl_xor(s, 8);
            lrow[r] += s;
        }
        __syncthreads();   // P visible (also orders vs next chunk's writes)

        half8_t pa0 = *(const half8_t*)&spw[lcol * 72 + quad * 8];
        half8_t pa1 = *(const half8_t*)&spw[lcol * 72 + 32 + quad * 8];
#pragma unroll
        for (int kp = 0; kp < 2; ++kp) {
            half8_t pa = kp ? pa1 : pa0;
            int nb = n0 + kp * 32 + quad * 8;
            {
                half8_t vf = *(const half8_t*)&vhh[(size_t)lcol * 1024 + nb];
                half8_t lf = *(const half8_t*)&vll[(size_t)lcol * 1024 + nb];
                o0 = __builtin_amdgcn_mfma_f32_16x16x32_f16(pa, vf, o0, 0, 0, 0);
                o0 = __builtin_amdgcn_mfma_f32_16x16x32_f16(pa, lf, o0, 0, 0, 0);
            }
            {
                half8_t vf = *(const half8_t*)&vhh[(size_t)(16 + lcol) * 1024 + nb];
                half8_t lf = *(const half8_t*)&vll[(size_t)(16 + lcol) * 1024 + nb];
                o1 = __builtin_amdgcn_mfma_f32_16x16x32_f16(pa, vf, o1, 0, 0, 0);
                o1 = __builtin_amdgcn_mfma_f32_16x16x32_f16(pa, lf, o1, 0, 0, 0);
            }
        }
        __syncthreads();
    }

#pragma unroll
    for (int r = 0; r < 4; ++r) {
        float inv = 1.f / lrow[r];
        int m = mwave + quad * 4 + r;
        out[((size_t)b * CC + head * 32 + lcol) * 1024 + m]      = o0[r] * inv;
        out[((size_t)b * CC + head * 32 + 16 + lcol) * 1024 + m] = o1[r] * inv;
    }
}

// ---------------------------------------------------------------------------
extern "C" void kernel_launch(void* const* d_in, const int* in_sizes, int n_in,
                              void* d_out, int out_size, void* d_ws, size_t ws_size,
                              hipStream_t stream) {
    const float* x   = (const float*)d_in[0];
    const float* Wq  = (const float*)d_in[1];
    const float* bq  = (const float*)d_in[2];
    const float* Wk  = (const float*)d_in[3];
    const float* bk  = (const float*)d_in[4];
    const float* Wv  = (const float*)d_in[5];
    const float* bv  = (const float*)d_in[6];
    const float* Wo  = (const float*)d_in[7];
    const float* bo  = (const float*)d_in[8];
    const float* dww = (const float*)d_in[9];
    const float* dwb = (const float*)d_in[10];
    const float* lng = (const float*)d_in[11];
    const float* lnb = (const float*)d_in[12];
    const float* pw  = (const float*)d_in[13];
    const float* rpe = (const float*)d_in[14];

    float* ws = (float*)d_ws;
    const size_t SZ = 786432;           // 2*384*1024 floats
    float* qbuf  = ws;
    float* xs    = ws + 1 * SZ;
    float* abuf  = ws + 2 * SZ;
    float* oconv = ws + 3 * SZ;         // 12*64*1024 = SZ
    _Float16* khT = (_Float16*)(ws + 4 * SZ);   // khT+klT share one SZ-float slab
    _Float16* klT = khT + 786432;
    _Float16* vhb = (_Float16*)(ws + 5 * SZ);   // vh+vl share one SZ-float slab
    _Float16* vlb = vhb + 786432;
    float* pos   = ws + 6 * SZ;         // 12*1024*2 floats

    dim3 gg(32, 6, 2);
    dim3 gg2(32, 6, 4);
    gemm_bias_kernel<0><<<gg, 256, 0, stream>>>(Wq, bq, nullptr, nullptr, x, qbuf, nullptr);
    dwconv_kernel<<<768, 256, 0, stream>>>(qbuf, dww, dwb, oconv);
    offset_kernel<<<dim3(12, 4), 256, 0, stream>>>(oconv, lng, lnb, pw, pos);
    sample_kernel<<<3072, 256, 0, stream>>>(x, pos, xs);
    gemm_kv_kernel<<<gg2, 256, 0, stream>>>(Wk, bk, Wv, bv, xs, khT, klT, vhb, vlb);
    attn_mfma_kernel<<<dim3(32, 24), 128, 0, stream>>>(qbuf, khT, klT, vhb, vlb, pos, rpe, abuf);
    gemm_bias_kernel<0><<<gg, 256, 0, stream>>>(Wo, bo, nullptr, nullptr, abuf, (float*)d_out, nullptr);
}

// Round 8
// 237.259 us; speedup vs baseline: 2.6191x; 1.2005x over previous
//
#include <hip/hip_runtime.h>
#include <hip/hip_fp16.h>
#include <math.h>

#define HH 32
#define WW 32
#define HWSZ 1024      // H*W
#define CC 384
#define NHEAD 12
#define NGROUP 6
#define HC 32
#define GC 64
#define NS 1024        // n_sample
#define ATTN_SCALE 0.17677669529663687f  // 32^-0.5

typedef _Float16 half8_t __attribute__((ext_vector_type(8)));
typedef _Float16 half4_t __attribute__((ext_vector_type(4)));
typedef _Float16 half2_t __attribute__((ext_vector_type(2)));
typedef float    f4_t    __attribute__((ext_vector_type(4)));

// ---------------------------------------------------------------------------
// 1x1-conv GEMM (fp32 out): Y[b,o,n] = sum_c W[o,c] X[b,c,n] + bias[o]
// 64m x 32n tile, BK=32, 4x2 microtile. Used for q and o projections.
// ---------------------------------------------------------------------------
template<int DUAL>
__global__ __launch_bounds__(256, 8) void gemm_bias_kernel(
    const float* __restrict__ W0, const float* __restrict__ bias0,
    const float* __restrict__ W1, const float* __restrict__ bias1,
    const float* __restrict__ X, float* __restrict__ Y0, float* __restrict__ Y1)
{
    int bz, which;
    if (DUAL) { bz = blockIdx.z >> 1; which = blockIdx.z & 1; }
    else      { bz = blockIdx.z;      which = 0; }
    const float* W    = which ? W1 : W0;
    const float* bias = which ? bias1 : bias0;
    float* Y          = which ? Y1 : Y0;

    const float* Xb = X + (size_t)bz * CC * 1024;
    float* Yb = Y + (size_t)bz * CC * 1024;
    const int tm = blockIdx.y * 64;
    const int tn = blockIdx.x * 32;
    const int tid = threadIdx.x;
    const int tx = tid & 15, ty = tid >> 4;

    __shared__ float sW[32][68];
    __shared__ float sX[32][36];

    float acc[4][2] = {};

    for (int k0 = 0; k0 < CC; k0 += 32) {
        {
            int idx = tid * 8;
            int m = idx >> 5;
            int kk = idx & 31;
            float4 wa = *(const float4*)&W[(size_t)(tm + m) * CC + k0 + kk];
            float4 wb = *(const float4*)&W[(size_t)(tm + m) * CC + k0 + kk + 4];
            sW[kk + 0][m] = wa.x; sW[kk + 1][m] = wa.y;
            sW[kk + 2][m] = wa.z; sW[kk + 3][m] = wa.w;
            sW[kk + 4][m] = wb.x; sW[kk + 5][m] = wb.y;
            sW[kk + 6][m] = wb.z; sW[kk + 7][m] = wb.w;
        }
        {
            int idx = tid * 4;
            int kk = idx >> 5;
            int n = idx & 31;
            *(float4*)&sX[kk][n] = *(const float4*)&Xb[(size_t)(k0 + kk) * 1024 + tn + n];
        }
        __syncthreads();
#pragma unroll
        for (int kk = 0; kk < 32; ++kk) {
            float a[4];
            *(float4*)a = *(const float4*)&sW[kk][ty * 4];
            float b0 = sX[kk][tx * 2], b1 = sX[kk][tx * 2 + 1];
#pragma unroll
            for (int i = 0; i < 4; ++i) {
                acc[i][0] += a[i] * b0;
                acc[i][1] += a[i] * b1;
            }
        }
        __syncthreads();
    }

#pragma unroll
    for (int i = 0; i < 4; ++i) {
        int m = tm + ty * 4 + i;
        float bv = bias[m];
        float2 r; r.x = acc[i][0] + bv; r.y = acc[i][1] + bv;
        *(float2*)&Yb[(size_t)m * 1024 + tn + tx * 2] = r;
    }
}

// ---------------------------------------------------------------------------
// K/V projection GEMM: epilogue emits f16 hi/lo splits in MFMA-B layouts:
//   K: khT/klT [bh][n=1024][hc=32];  V: vh/vl [bh][hc=32][n=1024]
// ---------------------------------------------------------------------------
__global__ __launch_bounds__(256, 8) void gemm_kv_kernel(
    const float* __restrict__ Wk, const float* __restrict__ bk,
    const float* __restrict__ Wv, const float* __restrict__ bv,
    const float* __restrict__ X,
    _Float16* __restrict__ khT, _Float16* __restrict__ klT,
    _Float16* __restrict__ vhb, _Float16* __restrict__ vlb)
{
    const int bz = blockIdx.z >> 1, which = blockIdx.z & 1;
    const float* W    = which ? Wv : Wk;
    const float* bias = which ? bv : bk;

    const float* Xb = X + (size_t)bz * CC * 1024;
    const int tm = blockIdx.y * 64;
    const int tn = blockIdx.x * 32;
    const int tid = threadIdx.x;
    const int tx = tid & 15, ty = tid >> 4;

    __shared__ float sW[32][68];
    __shared__ float sX[32][36];

    float acc[4][2] = {};

    for (int k0 = 0; k0 < CC; k0 += 32) {
        {
            int idx = tid * 8;
            int m = idx >> 5;
            int kk = idx & 31;
            float4 wa = *(const float4*)&W[(size_t)(tm + m) * CC + k0 + kk];
            float4 wb = *(const float4*)&W[(size_t)(tm + m) * CC + k0 + kk + 4];
            sW[kk + 0][m] = wa.x; sW[kk + 1][m] = wa.y;
            sW[kk + 2][m] = wa.z; sW[kk + 3][m] = wa.w;
            sW[kk + 4][m] = wb.x; sW[kk + 5][m] = wb.y;
            sW[kk + 6][m] = wb.z; sW[kk + 7][m] = wb.w;
        }
        {
            int idx = tid * 4;
            int kk = idx >> 5;
            int n = idx & 31;
            *(float4*)&sX[kk][n] = *(const float4*)&Xb[(size_t)(k0 + kk) * 1024 + tn + n];
        }
        __syncthreads();
#pragma unroll
        for (int kk = 0; kk < 32; ++kk) {
            float a[4];
            *(float4*)a = *(const float4*)&sW[kk][ty * 4];
            float b0 = sX[kk][tx * 2], b1 = sX[kk][tx * 2 + 1];
#pragma unroll
            for (int i = 0; i < 4; ++i) {
                acc[i][0] += a[i] * b0;
                acc[i][1] += a[i] * b1;
            }
        }
        __syncthreads();
    }

    const int ch0 = tm + ty * 4;
    const int head = ch0 >> 5, hc0 = ch0 & 31;
    const int bhh = bz * 12 + head;
    float bvs[4];
#pragma unroll
    for (int i = 0; i < 4; ++i) bvs[i] = bias[ch0 + i];

    if (which == 0) {   // K -> [n][hc]
#pragma unroll
        for (int j = 0; j < 2; ++j) {
            int n = tn + tx * 2 + j;
            half4_t hh, ll;
#pragma unroll
            for (int i = 0; i < 4; ++i) {
                float val = acc[i][j] + bvs[i];
                _Float16 h = (_Float16)val;
                hh[i] = h; ll[i] = (_Float16)(val - (float)h);
            }
            size_t base = ((size_t)bhh * 1024 + n) * 32 + hc0;
            *(half4_t*)&khT[base] = hh;
            *(half4_t*)&klT[base] = ll;
        }
    } else {            // V -> [hc][n]
#pragma unroll
        for (int i = 0; i < 4; ++i) {
            half2_t hh, ll;
#pragma unroll
            for (int j = 0; j < 2; ++j) {
                float val = acc[i][j] + bvs[i];
                _Float16 h = (_Float16)val;
                hh[j] = h; ll[j] = (_Float16)(val - (float)h);
            }
            size_t base = ((size_t)bhh * 32 + hc0 + i) * 1024 + tn + tx * 2;
            *(half2_t*)&vhb[base] = hh;
            *(half2_t*)&vlb[base] = ll;
        }
    }
}

// ---------------------------------------------------------------------------
// Depthwise 7x7 conv on q viewed as [12, 64, 32, 32]; zero pad 3.
// ---------------------------------------------------------------------------
__global__ __launch_bounds__(256) void dwconv_kernel(
    const float* __restrict__ q, const float* __restrict__ dww,
    const float* __restrict__ dwb, float* __restrict__ oconv)
{
    const int bc = blockIdx.x;
    const int bg = bc >> 6, c = bc & 63;
    const int b = bg / 6, g = bg % 6;
    const float* plane = q + ((size_t)b * CC + g * 64 + c) * 1024;

    __shared__ float sp[1024];
    __shared__ float sw[49];
    const int tid = threadIdx.x;
    for (int i = tid; i < 1024; i += 256) sp[i] = plane[i];
    if (tid < 49) sw[tid] = dww[c * 49 + tid];
    __syncthreads();

    const float bias = dwb[c];
    for (int i = tid; i < 1024; i += 256) {
        int y = i >> 5, x = i & 31;
        float s = 0.f;
#pragma unroll
        for (int ky = 0; ky < 7; ++ky) {
            int yy = y + ky - 3;
            if (yy < 0 || yy > 31) continue;
#pragma unroll
            for (int kx = 0; kx < 7; ++kx) {
                int xx = x + kx - 3;
                if (xx < 0 || xx > 31) continue;
                s += sp[yy * 32 + xx] * sw[ky * 7 + kx];
            }
        }
        oconv[(size_t)bc * 1024 + i] = s + bias;
    }
}

// ---------------------------------------------------------------------------
// LayerNorm(64 ch) + exact GELU + 1x1->2ch + tanh*2/32 + ref points.
// ---------------------------------------------------------------------------
__global__ __launch_bounds__(256) void offset_kernel(
    const float* __restrict__ oconv, const float* __restrict__ lng,
    const float* __restrict__ lnb, const float* __restrict__ pw,
    float* __restrict__ pos)
{
    const int bg = blockIdx.x;
    const int px = blockIdx.y * 256 + threadIdx.x;
    const float* base = oconv + (size_t)bg * 64 * 1024 + px;

    float col[64];
    float sum = 0.f;
#pragma unroll
    for (int c = 0; c < 64; ++c) { col[c] = base[(size_t)c * 1024]; sum += col[c]; }
    float mu = sum * (1.f / 64.f);
    float var = 0.f;
#pragma unroll
    for (int c = 0; c < 64; ++c) { float d = col[c] - mu; var += d * d; }
    float inv = rsqrtf(var * (1.f / 64.f) + 1e-5f);
    float offy = 0.f, offx = 0.f;
#pragma unroll
    for (int c = 0; c < 64; ++c) {
        float v = (col[c] - mu) * inv * lng[c] + lnb[c];
        float g = 0.5f * v * (1.f + erff(v * 0.70710678118654752440f));
        offy += g * pw[c];
        offx += g * pw[64 + c];
    }
    offy = tanhf(offy) * (2.0f / 32.0f);
    offx = tanhf(offx) * (2.0f / 32.0f);
    int y = px >> 5, x = px & 31;
    float ry = ((y + 0.5f) / 32.f) * 2.f - 1.f;
    float rx = ((x + 0.5f) / 32.f) * 2.f - 1.f;
    pos[((size_t)bg * 1024 + px) * 2 + 0] = offy + ry;
    pos[((size_t)bg * 1024 + px) * 2 + 1] = offx + rx;
}

// ---------------------------------------------------------------------------
// Bilinear grid-sample of x at pos (align_corners=True, zeros pad).
// ---------------------------------------------------------------------------
__global__ __launch_bounds__(256) void sample_kernel(
    const float* __restrict__ x, const float* __restrict__ pos,
    float* __restrict__ xs)
{
    const int idx = blockIdx.x * 256 + threadIdx.x;
    const int s = idx & 1023;
    const int bc = idx >> 10;
    const int c = bc % CC;
    const int b = bc / CC;
    const int bg = b * 6 + (c >> 6);

    float py = pos[((size_t)bg * 1024 + s) * 2 + 0];
    float px = pos[((size_t)bg * 1024 + s) * 2 + 1];
    float gx = (px + 1.f) * 0.5f * 31.f;
    float gy = (py + 1.f) * 0.5f * 31.f;
    float x0f = floorf(gx), y0f = floorf(gy);
    float wx = gx - x0f, wy = gy - y0f;
    int x0 = (int)x0f, y0 = (int)y0f;

    const float* plane = x + (size_t)bc * 1024;
    float acc = 0.f;
    if ((unsigned)x0       <= 31u && (unsigned)y0       <= 31u) acc += plane[y0 * 32 + x0]           * (1.f - wx) * (1.f - wy);
    if ((unsigned)(x0 + 1) <= 31u && (unsigned)y0       <= 31u) acc += plane[y0 * 32 + x0 + 1]       * wx * (1.f - wy);
    if ((unsigned)x0       <= 31u && (unsigned)(y0 + 1) <= 31u) acc += plane[(y0 + 1) * 32 + x0]     * (1.f - wx) * wy;
    if ((unsigned)(x0 + 1) <= 31u && (unsigned)(y0 + 1) <= 31u) acc += plane[(y0 + 1) * 32 + x0 + 1] * wx * wy;
    xs[idx] = acc;
}

// ---------------------------------------------------------------------------
// MFMA flash attention, K-split. Block = 256 thr (4 waves), all waves share
// one 16-query tile; wave w owns keys [w*256, w*256+256) in 4 chunks of 64.
// Online softmax per wave; partials (m,l,O) combined through LDS at the end.
// RPE table staged as half2 horizontal pairs: 2 ds_read_b32 taps per score.
// Fragment layouts (gfx950 16x16x32): A[m=lane&15][k=quad*8+j],
// B[k=quad*8+j][n=lane&15], C/D[row=quad*4+reg][col=lane&15].
// ---------------------------------------------------------------------------
__global__ __launch_bounds__(256) void attn_mfma_kernel(
    const float* __restrict__ q, const _Float16* __restrict__ khT,
    const _Float16* __restrict__ klT, const _Float16* __restrict__ vhb,
    const _Float16* __restrict__ vlb, const float* __restrict__ pos,
    const float* __restrict__ rpe, float* __restrict__ out)
{
    const int bh = blockIdx.y;
    const int b = bh / 12, head = bh % 12;
    const int bg = b * 6 + (head >> 1);
    const int mblk = blockIdx.x * 16;
    const int tid = threadIdx.x;
    const int w = tid >> 6, lane = tid & 63;
    const int quad = lane >> 4, lcol = lane & 15;

    __shared__ half2_t srpe2[63 * 63];            // 15.5KB: {t[y][x], t[y][x+1]}
    __shared__ float sq[16 * 36];                 // 2.3KB q tile [m][hc] (cml later)
    __shared__ __align__(16) _Float16 sp[4][16 * 72];  // 9.2KB P-bufs (comb later)

    const float* rp = rpe + (size_t)head * 3969;
    for (int i = tid; i < 3969; i += 256) {
        int xx = i % 63;
        float v0 = rp[i];
        float v1 = (xx < 62) ? rp[i + 1] : 0.f;
        half2_t hv; hv[0] = (_Float16)v0; hv[1] = (_Float16)v1;
        srpe2[i] = hv;
    }
    {
        const float* qb = q + ((size_t)b * CC + head * 32) * 1024 + mblk;
#pragma unroll
        for (int i = 0; i < 2; ++i) {
            int idx = i * 256 + tid;
            int m = idx & 15, hc = idx >> 4;
            sq[m * 36 + hc] = qb[(size_t)hc * 1024 + m];
        }
    }
    __syncthreads();

    // Q A-fragments (f16 hi/lo); query m = mblk + lcol, k = quad*8+j
    half8_t qh, ql;
    {
        const float* qrow = &sq[lcol * 36 + quad * 8];
#pragma unroll
        for (int j = 0; j < 8; ++j) {
            float v = qrow[j];
            _Float16 h = (_Float16)v;
            qh[j] = h; ql[j] = (_Float16)(v - (float)h);
        }
    }

    const float qyw = (((mblk >> 5) + 0.5f) * (1.f / 32.f)) * 2.f - 1.f;
    float qxr[4];
#pragma unroll
    for (int r = 0; r < 4; ++r)
        qxr[r] = (((mblk & 31) + quad * 4 + r + 0.5f) * (1.f / 32.f)) * 2.f - 1.f;

    const float2* pgv = (const float2*)(pos + (size_t)bg * 2048);
    const _Float16* khb = khT + (size_t)bh * 1024 * 32;
    const _Float16* klb = klT + (size_t)bh * 1024 * 32;
    const _Float16* vhh = vhb + (size_t)bh * 32 * 1024;
    const _Float16* vll = vlb + (size_t)bh * 32 * 1024;
    _Float16* spw = sp[w];

    f4_t o0 = {0.f, 0.f, 0.f, 0.f}, o1 = {0.f, 0.f, 0.f, 0.f};
    float mrow[4] = {-3.0e38f, -3.0e38f, -3.0e38f, -3.0e38f};
    float lrow[4] = {0.f, 0.f, 0.f, 0.f};

#pragma unroll 1
    for (int c = 0; c < 4; ++c) {
        const int n0 = w * 256 + c * 64;
        f4_t S[4];
#pragma unroll
        for (int t = 0; t < 4; ++t) {
            int key = n0 + t * 16 + lcol;
            half8_t kh = *(const half8_t*)&khb[(size_t)key * 32 + quad * 8];
            half8_t kl = *(const half8_t*)&klb[(size_t)key * 32 + quad * 8];
            f4_t s = {0.f, 0.f, 0.f, 0.f};
            s = __builtin_amdgcn_mfma_f32_16x16x32_f16(ql, kh, s, 0, 0, 0);
            s = __builtin_amdgcn_mfma_f32_16x16x32_f16(qh, kl, s, 0, 0, 0);
            s = __builtin_amdgcn_mfma_f32_16x16x32_f16(qh, kh, s, 0, 0, 0);
            // RPE bias: row pair taps from half2 LDS table
            float2 pp = pgv[key];
            float gy = (qyw - pp.x) * 15.5f + 31.f;
            float y0f = floorf(gy);
            float wy = gy - y0f;
            int ybase = (int)y0f * 63;
#pragma unroll
            for (int r = 0; r < 4; ++r) {
                float gx = (qxr[r] - pp.y) * 15.5f + 31.f;
                float x0f = floorf(gx);
                float wx = gx - x0f;
                int i00 = ybase + (int)x0f;
                half2_t p0 = srpe2[i00];
                half2_t p1 = srpe2[i00 + 63];
                float r00 = (float)p0[0], r01 = (float)p0[1];
                float r10 = (float)p1[0], r11 = (float)p1[1];
                float top = r00 + (r01 - r00) * wx;
                float bot = r10 + (r11 - r10) * wx;
                s[r] = s[r] * ATTN_SCALE + top + (bot - top) * wy;
            }
            S[t] = s;
        }

        // online softmax update (rows r; reduce across 16 key-lanes)
#pragma unroll
        for (int r = 0; r < 4; ++r) {
            float cm = fmaxf(fmaxf(S[0][r], S[1][r]), fmaxf(S[2][r], S[3][r]));
            cm = fmaxf(cm, __shfl_xor(cm, 1));
            cm = fmaxf(cm, __shfl_xor(cm, 2));
            cm = fmaxf(cm, __shfl_xor(cm, 4));
            cm = fmaxf(cm, __shfl_xor(cm, 8));
            float mnew = fmaxf(mrow[r], cm);
            float alpha = __expf(mrow[r] - mnew);
            mrow[r] = mnew;
            lrow[r] *= alpha;
            o0[r] *= alpha;
            o1[r] *= alpha;
        }
        float rs[4] = {0.f, 0.f, 0.f, 0.f};
#pragma unroll
        for (int t = 0; t < 4; ++t) {
#pragma unroll
            for (int r = 0; r < 4; ++r) {
                float p = __expf(S[t][r] - mrow[r]);
                rs[r] += p;
                spw[(quad * 4 + r) * 72 + t * 16 + lcol] = (_Float16)p;
            }
        }
#pragma unroll
        for (int r = 0; r < 4; ++r) {
            float s = rs[r];
            s += __shfl_xor(s, 1); s += __shfl_xor(s, 2);
            s += __shfl_xor(s, 4); s += __shfl_xor(s, 8);
            lrow[r] += s;
        }
        __syncthreads();   // drain P writes (symmetric across the 4 waves)

        half8_t pa0 = *(const half8_t*)&spw[lcol * 72 + quad * 8];
        half8_t pa1 = *(const half8_t*)&spw[lcol * 72 + 32 + quad * 8];
#pragma unroll
        for (int kp = 0; kp < 2; ++kp) {
            half8_t pa = kp ? pa1 : pa0;
            int nb = n0 + kp * 32 + quad * 8;
            {
                half8_t vf = *(const half8_t*)&vhh[(size_t)lcol * 1024 + nb];
                half8_t lf = *(const half8_t*)&vll[(size_t)lcol * 1024 + nb];
                o0 = __builtin_amdgcn_mfma_f32_16x16x32_f16(pa, vf, o0, 0, 0, 0);
                o0 = __builtin_amdgcn_mfma_f32_16x16x32_f16(pa, lf, o0, 0, 0, 0);
            }
            {
                half8_t vf = *(const half8_t*)&vhh[(size_t)(16 + lcol) * 1024 + nb];
                half8_t lf = *(const half8_t*)&vll[(size_t)(16 + lcol) * 1024 + nb];
                o1 = __builtin_amdgcn_mfma_f32_16x16x32_f16(pa, vf, o1, 0, 0, 0);
                o1 = __builtin_amdgcn_mfma_f32_16x16x32_f16(pa, lf, o1, 0, 0, 0);
            }
        }
        __syncthreads();   // P consumed before next chunk overwrites
    }

    // ---- cross-wave combine: comb aliases sp (each wave's slab = its own sp),
    //      cml aliases sq. Stride 36 floats -> 2-way (free) bank aliasing.
    float* comb = (float*)sp;
    float* cml = sq;
#pragma unroll
    for (int r = 0; r < 4; ++r) {
        int qq = quad * 4 + r;
        comb[(w * 16 + qq) * 36 + lcol]      = o0[r];
        comb[(w * 16 + qq) * 36 + 16 + lcol] = o1[r];
    }
    if (lcol == 0) {
#pragma unroll
        for (int r = 0; r < 4; ++r) {
            int qq = quad * 4 + r;
            cml[(w * 16 + qq) * 2]     = mrow[r];
            cml[(w * 16 + qq) * 2 + 1] = lrow[r];
        }
    }
    __syncthreads();

#pragma unroll
    for (int i = 0; i < 2; ++i) {
        int idx = tid + i * 256;
        int qq = idx >> 5, hc = idx & 31;
        float m0 = cml[(0 * 16 + qq) * 2], l0 = cml[(0 * 16 + qq) * 2 + 1];
        float m1 = cml[(1 * 16 + qq) * 2], l1 = cml[(1 * 16 + qq) * 2 + 1];
        float m2 = cml[(2 * 16 + qq) * 2], l2 = cml[(2 * 16 + qq) * 2 + 1];
        float m3 = cml[(3 * 16 + qq) * 2], l3 = cml[(3 * 16 + qq) * 2 + 1];
        float ms = fmaxf(fmaxf(m0, m1), fmaxf(m2, m3));
        float e0 = __expf(m0 - ms), e1 = __expf(m1 - ms);
        float e2 = __expf(m2 - ms), e3 = __expf(m3 - ms);
        float L = e0 * l0 + e1 * l1 + e2 * l2 + e3 * l3;
        float o = e0 * comb[(0 * 16 + qq) * 36 + hc]
                + e1 * comb[(1 * 16 + qq) * 36 + hc]
                + e2 * comb[(2 * 16 + qq) * 36 + hc]
                + e3 * comb[(3 * 16 + qq) * 36 + hc];
        out[((size_t)b * CC + head * 32 + hc) * 1024 + mblk + qq] = o / L;
    }
}

// ---------------------------------------------------------------------------
extern "C" void kernel_launch(void* const* d_in, const int* in_sizes, int n_in,
                              void* d_out, int out_size, void* d_ws, size_t ws_size,
                              hipStream_t stream) {
    const float* x   = (const float*)d_in[0];
    const float* Wq  = (const float*)d_in[1];
    const float* bq  = (const float*)d_in[2];
    const float* Wk  = (const float*)d_in[3];
    const float* bk  = (const float*)d_in[4];
    const float* Wv  = (const float*)d_in[5];
    const float* bv  = (const float*)d_in[6];
    const float* Wo  = (const float*)d_in[7];
    const float* bo  = (const float*)d_in[8];
    const float* dww = (const float*)d_in[9];
    const float* dwb = (const float*)d_in[10];
    const float* lng = (const float*)d_in[11];
    const float* lnb = (const float*)d_in[12];
    const float* pw  = (const float*)d_in[13];
    const float* rpe = (const float*)d_in[14];

    float* ws = (float*)d_ws;
    const size_t SZ = 786432;           // 2*384*1024 floats
    float* qbuf  = ws;
    float* xs    = ws + 1 * SZ;
    float* abuf  = ws + 2 * SZ;
    float* oconv = ws + 3 * SZ;
    _Float16* khT = (_Float16*)(ws + 4 * SZ);
    _Float16* klT = khT + 786432;
    _Float16* vhb = (_Float16*)(ws + 5 * SZ);
    _Float16* vlb = vhb + 786432;
    float* pos   = ws + 6 * SZ;

    dim3 gg(32, 6, 2);
    dim3 gg2(32, 6, 4);
    gemm_bias_kernel<0><<<gg, 256, 0, stream>>>(Wq, bq, nullptr, nullptr, x, qbuf, nullptr);
    dwconv_kernel<<<768, 256, 0, stream>>>(qbuf, dww, dwb, oconv);
    offset_kernel<<<dim3(12, 4), 256, 0, stream>>>(oconv, lng, lnb, pw, pos);
    sample_kernel<<<3072, 256, 0, stream>>>(x, pos, xs);
    gemm_kv_kernel<<<gg2, 256, 0, stream>>>(Wk, bk, Wv, bv, xs, khT, klT, vhb, vlb);
    attn_mfma_kernel<<<dim3(64, 24), 256, 0, stream>>>(qbuf, khT, klT, vhb, vlb, pos, rpe, abuf);
    gemm_bias_kernel<0><<<gg, 256, 0, stream>>>(Wo, bo, nullptr, nullptr, abuf, (float*)d_out, nullptr);
}

// Round 9
// 223.896 us; speedup vs baseline: 2.7754x; 1.0597x over previous
//
#include <hip/hip_runtime.h>
#include <hip/hip_fp16.h>
#include <math.h>

#define HH 32
#define WW 32
#define HWSZ 1024      // H*W
#define CC 384
#define NHEAD 12
#define NGROUP 6
#define HC 32
#define GC 64
#define NS 1024        // n_sample
#define ATTN_SCALE 0.17677669529663687f  // 32^-0.5

typedef _Float16 half8_t __attribute__((ext_vector_type(8)));
typedef _Float16 half4_t __attribute__((ext_vector_type(4)));
typedef _Float16 half2_t __attribute__((ext_vector_type(2)));
typedef float    f4_t    __attribute__((ext_vector_type(4)));

// ---------------------------------------------------------------------------
// 1x1-conv GEMM (fp32 out): Y[b,o,n] = sum_c W[o,c] X[b,c,n] + bias[o]
// 64m x 32n tile, BK=32, 4x2 microtile. Used for q and o projections.
// ---------------------------------------------------------------------------
template<int DUAL>
__global__ __launch_bounds__(256, 8) void gemm_bias_kernel(
    const float* __restrict__ W0, const float* __restrict__ bias0,
    const float* __restrict__ W1, const float* __restrict__ bias1,
    const float* __restrict__ X, float* __restrict__ Y0, float* __restrict__ Y1)
{
    int bz, which;
    if (DUAL) { bz = blockIdx.z >> 1; which = blockIdx.z & 1; }
    else      { bz = blockIdx.z;      which = 0; }
    const float* W    = which ? W1 : W0;
    const float* bias = which ? bias1 : bias0;
    float* Y          = which ? Y1 : Y0;

    const float* Xb = X + (size_t)bz * CC * 1024;
    float* Yb = Y + (size_t)bz * CC * 1024;
    const int tm = blockIdx.y * 64;
    const int tn = blockIdx.x * 32;
    const int tid = threadIdx.x;
    const int tx = tid & 15, ty = tid >> 4;

    __shared__ float sW[32][68];
    __shared__ float sX[32][36];

    float acc[4][2] = {};

    for (int k0 = 0; k0 < CC; k0 += 32) {
        {
            int idx = tid * 8;
            int m = idx >> 5;
            int kk = idx & 31;
            float4 wa = *(const float4*)&W[(size_t)(tm + m) * CC + k0 + kk];
            float4 wb = *(const float4*)&W[(size_t)(tm + m) * CC + k0 + kk + 4];
            sW[kk + 0][m] = wa.x; sW[kk + 1][m] = wa.y;
            sW[kk + 2][m] = wa.z; sW[kk + 3][m] = wa.w;
            sW[kk + 4][m] = wb.x; sW[kk + 5][m] = wb.y;
            sW[kk + 6][m] = wb.z; sW[kk + 7][m] = wb.w;
        }
        {
            int idx = tid * 4;
            int kk = idx >> 5;
            int n = idx & 31;
            *(float4*)&sX[kk][n] = *(const float4*)&Xb[(size_t)(k0 + kk) * 1024 + tn + n];
        }
        __syncthreads();
#pragma unroll
        for (int kk = 0; kk < 32; ++kk) {
            float a[4];
            *(float4*)a = *(const float4*)&sW[kk][ty * 4];
            float b0 = sX[kk][tx * 2], b1 = sX[kk][tx * 2 + 1];
#pragma unroll
            for (int i = 0; i < 4; ++i) {
                acc[i][0] += a[i] * b0;
                acc[i][1] += a[i] * b1;
            }
        }
        __syncthreads();
    }

#pragma unroll
    for (int i = 0; i < 4; ++i) {
        int m = tm + ty * 4 + i;
        float bv = bias[m];
        float2 r; r.x = acc[i][0] + bv; r.y = acc[i][1] + bv;
        *(float2*)&Yb[(size_t)m * 1024 + tn + tx * 2] = r;
    }
}

// ---------------------------------------------------------------------------
// K/V projection GEMM: epilogue emits f16 in MFMA-friendly layouts:
//   K: khT [bh][n=1024][hc=32];  V: vh [bh][hc=32][n=1024]
// ---------------------------------------------------------------------------
__global__ __launch_bounds__(256, 8) void gemm_kv_kernel(
    const float* __restrict__ Wk, const float* __restrict__ bk,
    const float* __restrict__ Wv, const float* __restrict__ bv,
    const float* __restrict__ X,
    _Float16* __restrict__ khT, _Float16* __restrict__ vhb)
{
    const int bz = blockIdx.z >> 1, which = blockIdx.z & 1;
    const float* W    = which ? Wv : Wk;
    const float* bias = which ? bv : bk;

    const float* Xb = X + (size_t)bz * CC * 1024;
    const int tm = blockIdx.y * 64;
    const int tn = blockIdx.x * 32;
    const int tid = threadIdx.x;
    const int tx = tid & 15, ty = tid >> 4;

    __shared__ float sW[32][68];
    __shared__ float sX[32][36];

    float acc[4][2] = {};

    for (int k0 = 0; k0 < CC; k0 += 32) {
        {
            int idx = tid * 8;
            int m = idx >> 5;
            int kk = idx & 31;
            float4 wa = *(const float4*)&W[(size_t)(tm + m) * CC + k0 + kk];
            float4 wb = *(const float4*)&W[(size_t)(tm + m) * CC + k0 + kk + 4];
            sW[kk + 0][m] = wa.x; sW[kk + 1][m] = wa.y;
            sW[kk + 2][m] = wa.z; sW[kk + 3][m] = wa.w;
            sW[kk + 4][m] = wb.x; sW[kk + 5][m] = wb.y;
            sW[kk + 6][m] = wb.z; sW[kk + 7][m] = wb.w;
        }
        {
            int idx = tid * 4;
            int kk = idx >> 5;
            int n = idx & 31;
            *(float4*)&sX[kk][n] = *(const float4*)&Xb[(size_t)(k0 + kk) * 1024 + tn + n];
        }
        __syncthreads();
#pragma unroll
        for (int kk = 0; kk < 32; ++kk) {
            float a[4];
            *(float4*)a = *(const float4*)&sW[kk][ty * 4];
            float b0 = sX[kk][tx * 2], b1 = sX[kk][tx * 2 + 1];
#pragma unroll
            for (int i = 0; i < 4; ++i) {
                acc[i][0] += a[i] * b0;
                acc[i][1] += a[i] * b1;
            }
        }
        __syncthreads();
    }

    const int ch0 = tm + ty * 4;
    const int head = ch0 >> 5, hc0 = ch0 & 31;
    const int bhh = bz * 12 + head;
    float bvs[4];
#pragma unroll
    for (int i = 0; i < 4; ++i) bvs[i] = bias[ch0 + i];

    if (which == 0) {   // K -> [n][hc]
#pragma unroll
        for (int j = 0; j < 2; ++j) {
            int n = tn + tx * 2 + j;
            half4_t hh;
#pragma unroll
            for (int i = 0; i < 4; ++i) hh[i] = (_Float16)(acc[i][j] + bvs[i]);
            *(half4_t*)&khT[((size_t)bhh * 1024 + n) * 32 + hc0] = hh;
        }
    } else {            // V -> [hc][n]
#pragma unroll
        for (int i = 0; i < 4; ++i) {
            half2_t hh;
#pragma unroll
            for (int j = 0; j < 2; ++j) hh[j] = (_Float16)(acc[i][j] + bvs[i]);
            *(half2_t*)&vhb[((size_t)bhh * 32 + hc0 + i) * 1024 + tn + tx * 2] = hh;
        }
    }
}

// ---------------------------------------------------------------------------
// Depthwise 7x7 conv on q viewed as [12, 64, 32, 32]; zero pad 3.
// ---------------------------------------------------------------------------
__global__ __launch_bounds__(256) void dwconv_kernel(
    const float* __restrict__ q, const float* __restrict__ dww,
    const float* __restrict__ dwb, float* __restrict__ oconv)
{
    const int bc = blockIdx.x;
    const int bg = bc >> 6, c = bc & 63;
    const int b = bg / 6, g = bg % 6;
    const float* plane = q + ((size_t)b * CC + g * 64 + c) * 1024;

    __shared__ float sp[1024];
    __shared__ float sw[49];
    const int tid = threadIdx.x;
    for (int i = tid; i < 1024; i += 256) sp[i] = plane[i];
    if (tid < 49) sw[tid] = dww[c * 49 + tid];
    __syncthreads();

    const float bias = dwb[c];
    for (int i = tid; i < 1024; i += 256) {
        int y = i >> 5, x = i & 31;
        float s = 0.f;
#pragma unroll
        for (int ky = 0; ky < 7; ++ky) {
            int yy = y + ky - 3;
            if (yy < 0 || yy > 31) continue;
#pragma unroll
            for (int kx = 0; kx < 7; ++kx) {
                int xx = x + kx - 3;
                if (xx < 0 || xx > 31) continue;
                s += sp[yy * 32 + xx] * sw[ky * 7 + kx];
            }
        }
        oconv[(size_t)bc * 1024 + i] = s + bias;
    }
}

// ---------------------------------------------------------------------------
// LayerNorm(64 ch) + exact GELU + 1x1->2ch + tanh*2/32 + ref points.
// ---------------------------------------------------------------------------
__global__ __launch_bounds__(256) void offset_kernel(
    const float* __restrict__ oconv, const float* __restrict__ lng,
    const float* __restrict__ lnb, const float* __restrict__ pw,
    float* __restrict__ pos)
{
    const int bg = blockIdx.x;
    const int px = blockIdx.y * 256 + threadIdx.x;
    const float* base = oconv + (size_t)bg * 64 * 1024 + px;

    float col[64];
    float sum = 0.f;
#pragma unroll
    for (int c = 0; c < 64; ++c) { col[c] = base[(size_t)c * 1024]; sum += col[c]; }
    float mu = sum * (1.f / 64.f);
    float var = 0.f;
#pragma unroll
    for (int c = 0; c < 64; ++c) { float d = col[c] - mu; var += d * d; }
    float inv = rsqrtf(var * (1.f / 64.f) + 1e-5f);
    float offy = 0.f, offx = 0.f;
#pragma unroll
    for (int c = 0; c < 64; ++c) {
        float v = (col[c] - mu) * inv * lng[c] + lnb[c];
        float g = 0.5f * v * (1.f + erff(v * 0.70710678118654752440f));
        offy += g * pw[c];
        offx += g * pw[64 + c];
    }
    offy = tanhf(offy) * (2.0f / 32.0f);
    offx = tanhf(offx) * (2.0f / 32.0f);
    int y = px >> 5, x = px & 31;
    float ry = ((y + 0.5f) / 32.f) * 2.f - 1.f;
    float rx = ((x + 0.5f) / 32.f) * 2.f - 1.f;
    pos[((size_t)bg * 1024 + px) * 2 + 0] = offy + ry;
    pos[((size_t)bg * 1024 + px) * 2 + 1] = offx + rx;
}

// ---------------------------------------------------------------------------
// Bilinear grid-sample of x at pos (align_corners=True, zeros pad).
// ---------------------------------------------------------------------------
__global__ __launch_bounds__(256) void sample_kernel(
    const float* __restrict__ x, const float* __restrict__ pos,
    float* __restrict__ xs)
{
    const int idx = blockIdx.x * 256 + threadIdx.x;
    const int s = idx & 1023;
    const int bc = idx >> 10;
    const int c = bc % CC;
    const int b = bc / CC;
    const int bg = b * 6 + (c >> 6);

    float py = pos[((size_t)bg * 1024 + s) * 2 + 0];
    float px = pos[((size_t)bg * 1024 + s) * 2 + 1];
    float gx = (px + 1.f) * 0.5f * 31.f;
    float gy = (py + 1.f) * 0.5f * 31.f;
    float x0f = floorf(gx), y0f = floorf(gy);
    float wx = gx - x0f, wy = gy - y0f;
    int x0 = (int)x0f, y0 = (int)y0f;

    const float* plane = x + (size_t)bc * 1024;
    float acc = 0.f;
    if ((unsigned)x0       <= 31u && (unsigned)y0       <= 31u) acc += plane[y0 * 32 + x0]           * (1.f - wx) * (1.f - wy);
    if ((unsigned)(x0 + 1) <= 31u && (unsigned)y0       <= 31u) acc += plane[y0 * 32 + x0 + 1]       * wx * (1.f - wy);
    if ((unsigned)x0       <= 31u && (unsigned)(y0 + 1) <= 31u) acc += plane[(y0 + 1) * 32 + x0]     * (1.f - wx) * wy;
    if ((unsigned)(x0 + 1) <= 31u && (unsigned)(y0 + 1) <= 31u) acc += plane[(y0 + 1) * 32 + x0 + 1] * wx * wy;
    xs[idx] = acc;
}

// ---------------------------------------------------------------------------
// MFMA flash attention, transposed dataflow (S^T = K·Q^T), K-split 4 waves.
// Block = 256 thr; wave w owns keys [w*256, +256) of one 16-query tile.
// - S^T C-layout: rows=keys(quad*4+r), cols=queries(lcol) -> per-lane query,
//   softmax reduce = 2 shuffles (xor 16,32).
// - RPE taps: gx varies smoothly across lanes -> ~consecutive LDS addresses.
// - PV: O^T = V^T·P^T; P^T B-frag via wave-private LDS slab, NO barrier
//   (wave-synchronous LDS: lockstep wave64 + compiler lgkmcnt).
// - Pure f16 Q/K/V (error budget: P-f16 storage dominates at 4.9e-4 rel).
// Zero __syncthreads() in the K-loop; waves fully independent until combine.
// ---------------------------------------------------------------------------
__global__ __launch_bounds__(256) void attn_mfma_kernel(
    const float* __restrict__ q, const _Float16* __restrict__ khT,
    const _Float16* __restrict__ vhb, const float* __restrict__ pos,
    const float* __restrict__ rpe, float* __restrict__ out)
{
    const int bh = blockIdx.y;
    const int b = bh / 12, head = bh % 12;
    const int bg = b * 6 + (head >> 1);
    const int mblk = blockIdx.x * 16;      // 16 queries, one image row
    const int tid = threadIdx.x;
    const int w = tid >> 6, lane = tid & 63;
    const int quad = lane >> 4, lcol = lane & 15;

    // LDS plan: srpe2 @0 (15876B, reused as comb 9216B after loop),
    //           sqh @15888 (1024B), sp @16912 (4x2304B), cml @26128 (512B)
    __shared__ __align__(16) char smem[26640];
    half2_t*  srpe2 = (half2_t*)smem;
    _Float16* sqh   = (_Float16*)(smem + 15888);
    _Float16* spw   = (_Float16*)(smem + 16912) + w * (16 * 72);
    float*    cml   = (float*)(smem + 26128);
    float*    comb  = (float*)smem;

    const float* rp = rpe + (size_t)head * 3969;
    for (int i = tid; i < 3969; i += 256) {
        int xx = i % 63;
        float v0 = rp[i];
        float v1 = (xx < 62) ? rp[i + 1] : 0.f;
        half2_t hv; hv[0] = (_Float16)v0; hv[1] = (_Float16)v1;
        srpe2[i] = hv;
    }
    {
        const float* qb = q + ((size_t)b * CC + head * 32) * 1024 + mblk;
        for (int i = tid; i < 512; i += 256) {
            int hc = i >> 4, m = i & 15;
            sqh[m * 32 + hc] = (_Float16)qb[(size_t)hc * 1024 + m];
        }
    }
    __syncthreads();

    // Q^T B-frag: B[k=hc=quad*8+j][n=query=lcol]
    half8_t qf = *(const half8_t*)&sqh[lcol * 32 + quad * 8];

    const float qyw = (((mblk >> 5) + 0.5f) * (1.f / 32.f)) * 2.f - 1.f;
    const float qx  = (((mblk & 31) + lcol + 0.5f) * (1.f / 32.f)) * 2.f - 1.f;

    const float2* pgv = (const float2*)(pos + (size_t)bg * 2048);
    const _Float16* khb = khT + (size_t)bh * 1024 * 32;
    const _Float16* vhh = vhb + (size_t)bh * 32 * 1024;

    f4_t o0 = {0.f, 0.f, 0.f, 0.f}, o1 = {0.f, 0.f, 0.f, 0.f};
    float mrun = -3.0e38f, lrun = 0.f;     // per-lane query state

#pragma unroll 1
    for (int c = 0; c < 4; ++c) {
        const int n0 = w * 256 + c * 64;
        f4_t S[4];
#pragma unroll
        for (int t = 0; t < 4; ++t) {
            // A-frag K: A[m=key=lcol][k=hc=quad*8+j]
            half8_t kh = *(const half8_t*)&khb[(size_t)(n0 + t * 16 + lcol) * 32 + quad * 8];
            f4_t s = {0.f, 0.f, 0.f, 0.f};
            s = __builtin_amdgcn_mfma_f32_16x16x32_f16(kh, qf, s, 0, 0, 0);
            // RPE: rows = keys quad*4+r (pos broadcast in quad), col = query lcol
#pragma unroll
            for (int r = 0; r < 4; ++r) {
                int key = n0 + t * 16 + quad * 4 + r;
                float2 pp = pgv[key];
                float gy = (qyw - pp.x) * 15.5f + 31.f;
                float gx = (qx  - pp.y) * 15.5f + 31.f;
                float y0f = floorf(gy), x0f = floorf(gx);
                float wy = gy - y0f, wx = gx - x0f;
                int i00 = (int)y0f * 63 + (int)x0f;
                half2_t p0 = srpe2[i00];
                half2_t p1 = srpe2[i00 + 63];
                float r00 = (float)p0[0], r01 = (float)p0[1];
                float r10 = (float)p1[0], r11 = (float)p1[1];
                float top = r00 + (r01 - r00) * wx;
                float bot = r10 + (r11 - r10) * wx;
                s[r] = s[r] * ATTN_SCALE + top + (bot - top) * wy;
            }
            S[t] = s;
        }

        // online softmax for this chunk (per-lane query; reduce keys)
        float cm = -3.0e38f;
#pragma unroll
        for (int t = 0; t < 4; ++t)
            cm = fmaxf(cm, fmaxf(fmaxf(S[t][0], S[t][1]), fmaxf(S[t][2], S[t][3])));
        cm = fmaxf(cm, __shfl_xor(cm, 16));
        cm = fmaxf(cm, __shfl_xor(cm, 32));
        float mnew = fmaxf(mrun, cm);
        float alpha = __expf(mrun - mnew);
        mrun = mnew;

        float rs = 0.f;
#pragma unroll
        for (int t = 0; t < 4; ++t) {
            float p0 = __expf(S[t][0] - mnew);
            float p1 = __expf(S[t][1] - mnew);
            float p2 = __expf(S[t][2] - mnew);
            float p3 = __expf(S[t][3] - mnew);
            rs += (p0 + p1) + (p2 + p3);
            half4_t h;
            h[0] = (_Float16)p0; h[1] = (_Float16)p1;
            h[2] = (_Float16)p2; h[3] = (_Float16)p3;
            *(half4_t*)&spw[lcol * 72 + t * 16 + quad * 4] = h;   // P^T[query][key]
        }
        rs += __shfl_xor(rs, 16);
        rs += __shfl_xor(rs, 32);
        lrun = lrun * alpha + rs;
        o0 *= alpha; o1 *= alpha;

        // PV: O^T += V^T · P^T  (wave-internal LDS read-back; no barrier)
#pragma unroll
        for (int kp = 0; kp < 2; ++kp) {
            half8_t pb = *(const half8_t*)&spw[lcol * 72 + kp * 32 + quad * 8];
            int nb = n0 + kp * 32 + quad * 8;
            half8_t v0 = *(const half8_t*)&vhh[(size_t)lcol * 1024 + nb];
            half8_t v1 = *(const half8_t*)&vhh[(size_t)(16 + lcol) * 1024 + nb];
            o0 = __builtin_amdgcn_mfma_f32_16x16x32_f16(v0, pb, o0, 0, 0, 0);
            o1 = __builtin_amdgcn_mfma_f32_16x16x32_f16(v1, pb, o1, 0, 0, 0);
        }
    }

    __syncthreads();   // all waves done with srpe2 -> safe to alias as comb

    // O^T D-layout: o0[r]=O^T[hc=quad*4+r][query=lcol], o1: hc+16
    *(f4_t*)&comb[(w * 16 + lcol) * 36 + quad * 4]      = o0;
    *(f4_t*)&comb[(w * 16 + lcol) * 36 + 16 + quad * 4] = o1;
    if (quad == 0) {
        cml[(w * 16 + lcol) * 2]     = mrun;
        cml[(w * 16 + lcol) * 2 + 1] = lrun;
    }
    __syncthreads();

#pragma unroll
    for (int i = 0; i < 2; ++i) {
        int idx = tid + i * 256;
        int qq = idx >> 5, hc = idx & 31;
        float m0 = cml[(0 * 16 + qq) * 2], l0 = cml[(0 * 16 + qq) * 2 + 1];
        float m1 = cml[(1 * 16 + qq) * 2], l1 = cml[(1 * 16 + qq) * 2 + 1];
        float m2 = cml[(2 * 16 + qq) * 2], l2 = cml[(2 * 16 + qq) * 2 + 1];
        float m3 = cml[(3 * 16 + qq) * 2], l3 = cml[(3 * 16 + qq) * 2 + 1];
        float ms = fmaxf(fmaxf(m0, m1), fmaxf(m2, m3));
        float e0 = __expf(m0 - ms), e1 = __expf(m1 - ms);
        float e2 = __expf(m2 - ms), e3 = __expf(m3 - ms);
        float L = e0 * l0 + e1 * l1 + e2 * l2 + e3 * l3;
        float o = e0 * comb[(0 * 16 + qq) * 36 + hc]
                + e1 * comb[(1 * 16 + qq) * 36 + hc]
                + e2 * comb[(2 * 16 + qq) * 36 + hc]
                + e3 * comb[(3 * 16 + qq) * 36 + hc];
        out[((size_t)b * CC + head * 32 + hc) * 1024 + mblk + qq] = o / L;
    }
}

// ---------------------------------------------------------------------------
extern "C" void kernel_launch(void* const* d_in, const int* in_sizes, int n_in,
                              void* d_out, int out_size, void* d_ws, size_t ws_size,
                              hipStream_t stream) {
    const float* x   = (const float*)d_in[0];
    const float* Wq  = (const float*)d_in[1];
    const float* bq  = (const float*)d_in[2];
    const float* Wk  = (const float*)d_in[3];
    const float* bk  = (const float*)d_in[4];
    const float* Wv  = (const float*)d_in[5];
    const float* bv  = (const float*)d_in[6];
    const float* Wo  = (const float*)d_in[7];
    const float* bo  = (const float*)d_in[8];
    const float* dww = (const float*)d_in[9];
    const float* dwb = (const float*)d_in[10];
    const float* lng = (const float*)d_in[11];
    const float* lnb = (const float*)d_in[12];
    const float* pw  = (const float*)d_in[13];
    const float* rpe = (const float*)d_in[14];

    float* ws = (float*)d_ws;
    const size_t SZ = 786432;           // 2*384*1024 floats
    float* qbuf  = ws;
    float* xs    = ws + 1 * SZ;
    float* abuf  = ws + 2 * SZ;
    float* oconv = ws + 3 * SZ;
    _Float16* khT = (_Float16*)(ws + 4 * SZ);   // 1.5MB in a 3MB slab
    _Float16* vhb = (_Float16*)(ws + 5 * SZ);
    float* pos   = ws + 6 * SZ;

    dim3 gg(32, 6, 2);
    dim3 gg2(32, 6, 4);
    gemm_bias_kernel<0><<<gg, 256, 0, stream>>>(Wq, bq, nullptr, nullptr, x, qbuf, nullptr);
    dwconv_kernel<<<768, 256, 0, stream>>>(qbuf, dww, dwb, oconv);
    offset_kernel<<<dim3(12, 4), 256, 0, stream>>>(oconv, lng, lnb, pw, pos);
    sample_kernel<<<3072, 256, 0, stream>>>(x, pos, xs);
    gemm_kv_kernel<<<gg2, 256, 0, stream>>>(Wk, bk, Wv, bv, xs, khT, vhb);
    attn_mfma_kernel<<<dim3(64, 24), 256, 0, stream>>>(qbuf, khT, vhb, pos, rpe, abuf);
    gemm_bias_kernel<0><<<gg, 256, 0, stream>>>(Wo, bo, nullptr, nullptr, abuf, (float*)d_out, nullptr);
}